// Round 22
// baseline (323.332 us; speedup 1.0000x reference)
//
#include <hip/hip_runtime.h>

#define EPSF 1e-7f
#define NBMAX 512   // max dst-buckets (ceil(N/128)); N=50000 -> 391

typedef __attribute__((ext_vector_type(4))) _Float16 half4;
typedef __attribute__((ext_vector_type(8))) _Float16 half8;
typedef __attribute__((ext_vector_type(2))) _Float16 half2v;
typedef __attribute__((ext_vector_type(4))) float f32x4;
typedef unsigned long long u64;

__device__ __forceinline__ float lrelu02(float x){ return x > 0.f ? x : 0.2f*x; }

// ---------------- CSR build (bucket-local, no N-sized scan) ----------------
__global__ __launch_bounds__(256) void k_bhist(
    const int* __restrict__ dst0, int E0, const int* __restrict__ dst1, int E1,
    int* __restrict__ bcnt0, int* __restrict__ bcnt1, int nb) {
  __shared__ int h0[NBMAX], h1[NBMAX];
  const int tid = threadIdx.x;
  const int g = blockIdx.x*blockDim.x + tid;
  const int stride = gridDim.x*blockDim.x;
  for (int i = tid; i < nb; i += 256) { h0[i] = 0; h1[i] = 0; }
  __syncthreads();
  for (int i = g; i < E0; i += stride) atomicAdd(&h0[dst0[i] >> 7], 1);
  for (int i = g; i < E1; i += stride) atomicAdd(&h1[dst1[i] >> 7], 1);
  __syncthreads();
  for (int i = tid; i < nb; i += 256) {
    if (h0[i]) atomicAdd(&bcnt0[i], h0[i]);
    if (h1[i]) atomicAdd(&bcnt1[i], h1[i]);
  }
}

__global__ __launch_bounds__(1024) void k_bscan(
    const int* __restrict__ bcnt0, int* __restrict__ bbase0, int* __restrict__ bcur0,
    const int* __restrict__ bcnt1, int* __restrict__ bbase1, int* __restrict__ bcur1,
    int nb) {
  __shared__ int wt[16];
  const int tid = threadIdx.x;
  const int half = tid >> 9, idx = tid & 511;
  const int* bcnt = half ? bcnt1 : bcnt0;
  int* bbase = half ? bbase1 : bbase0;
  int* bcur  = half ? bcur1  : bcur0;
  int v = (idx < nb) ? bcnt[idx] : 0;
  const int lane = tid & 63, w = tid >> 6;
  int inc = v;
  #pragma unroll
  for (int o = 1; o < 64; o <<= 1) { int t = __shfl_up(inc, o); if (lane >= o) inc += t; }
  if (lane == 63) wt[w] = inc;
  __syncthreads();
  int woff = 0;
  for (int i = half*8; i < w; ++i) woff += wt[i];
  int excl = woff + inc - v;
  if (idx < nb) { bbase[idx] = excl; bcur[idx] = excl; }
  if (idx == nb-1) bbase[nb] = excl + v;
}

__global__ __launch_bounds__(256) void k_bucketA(
    const int* __restrict__ src0, const int* __restrict__ dst0,
    int* __restrict__ bcur0, u64* __restrict__ temp0, int E0, int blocksA0,
    const int* __restrict__ src1, const int* __restrict__ dst1,
    int* __restrict__ bcur1, u64* __restrict__ temp1, int E1, int nb) {
  const int g0 = (blockIdx.x < blocksA0);
  const int* src = g0 ? src0 : src1;
  const int* dst = g0 ? dst0 : dst1;
  int* bcur      = g0 ? bcur0 : bcur1;
  u64* temp      = g0 ? temp0 : temp1;
  const int E    = g0 ? E0 : E1;
  const int cb   = g0 ? blockIdx.x : blockIdx.x - blocksA0;
  __shared__ int hist[NBMAX];
  __shared__ int lbase[NBMAX];
  const int tid = threadIdx.x;
  const int chunk0 = cb * 4096;
  const int e_end = min(chunk0 + 4096, E);
  for (int i = tid; i < nb; i += 256) hist[i] = 0;
  __syncthreads();
  for (int i = chunk0 + tid; i < e_end; i += 256)
    atomicAdd(&hist[dst[i] >> 7], 1);
  __syncthreads();
  for (int bn = tid; bn < nb; bn += 256) {
    int c = hist[bn];
    lbase[bn] = c ? atomicAdd(&bcur[bn], c) : 0;
    hist[bn] = 0;
  }
  __syncthreads();
  for (int i = chunk0 + tid; i < e_end; i += 256) {
    int d = dst[i];
    int bn = d >> 7;
    int off = atomicAdd(&hist[bn], 1);
    temp[(size_t)lbase[bn] + off] = ((u64)(unsigned)d << 32) | (unsigned)src[i];
  }
}

// pass B: per bucket, per-dst count + local scan -> rowptr; scatter csrc.
// For graph 0 additionally: per-edge attention weights (fp16).
__global__ __launch_bounds__(256) void k_bucketB2(
    const u64* __restrict__ temp0, const int* __restrict__ bbase0,
    int* __restrict__ rowptr0, int* __restrict__ csrc0,
    const float* __restrict__ es1, const float* __restrict__ ed1,
    half4* __restrict__ w0,
    const u64* __restrict__ temp1, const int* __restrict__ bbase1,
    int* __restrict__ rowptr1, int* __restrict__ csrc1, int N, int nb) {
  const int g0 = (blockIdx.x < nb);
  const u64* temp = g0 ? temp0 : temp1;
  const int* bbase = g0 ? bbase0 : bbase1;
  int* rowptr = g0 ? rowptr0 : rowptr1;
  int* csrc   = g0 ? csrc0 : csrc1;
  const int b = g0 ? blockIdx.x : blockIdx.x - nb;
  __shared__ int lcnt[128];
  __shared__ int lcur[128];
  __shared__ int wt4[4];
  __shared__ float ledv[512];
  const int tid = threadIdx.x;
  const int d0 = b << 7;
  const int d1 = min(d0 + 128, N);
  const int lo = bbase[b], hi = bbase[b+1];
  if (tid < 128) lcnt[tid] = 0;
  if (g0) {
    for (int i = tid; i < (d1 - d0)*4; i += 256) ledv[i] = ed1[d0*4 + i];
  }
  __syncthreads();
  for (int k = lo + tid; k < hi; k += 256)
    atomicAdd(&lcnt[(int)(temp[k] >> 32) - d0], 1);
  __syncthreads();
  int v = (tid < 128) ? lcnt[tid] : 0;
  const int lane = tid & 63, w = tid >> 6;
  int inc = v;
  #pragma unroll
  for (int o = 1; o < 64; o <<= 1) { int t = __shfl_up(inc, o); if (lane >= o) inc += t; }
  if (lane == 63) wt4[w] = inc;
  __syncthreads();
  int woff = 0;
  for (int i = 0; i < w; ++i) woff += wt4[i];
  int excl = lo + woff + inc - v;
  if (tid < d1 - d0) { rowptr[d0 + tid] = excl; lcur[tid] = excl; }
  if (b == nb-1 && tid == 0) rowptr[N] = hi;
  __syncthreads();
  for (int k = lo + tid; k < hi; k += 256) {
    u64 p = temp[k];
    int d = (int)(p >> 32);
    int s = (int)(unsigned)p;
    int pos = atomicAdd(&lcur[d - d0], 1);
    csrc[pos] = s;
    if (g0) {
      float4 e = *(const float4*)(es1 + (size_t)s*4);
      int ld = (d - d0)*4;
      half4 wh;
      wh.x = (_Float16)__expf(lrelu02(e.x + ledv[ld+0]));
      wh.y = (_Float16)__expf(lrelu02(e.y + ledv[ld+1]));
      wh.z = (_Float16)__expf(lrelu02(e.z + ledv[ld+2]));
      wh.w = (_Float16)__expf(lrelu02(e.w + ledv[ld+3]));
      w0[pos] = wh;
    }
  }
}

// ------------- w1a/w1b [128][4]: w1a[k][h] = sum_j W1[k][h*64+j]*a_src[h][j] -------------
__global__ __launch_bounds__(512) void k_w1ab(
    const float* __restrict__ W1, const float* __restrict__ a_src,
    const float* __restrict__ a_dst, float* __restrict__ w1a, float* __restrict__ w1b) {
  const int t = threadIdx.x;
  const int k = t & 127, h = t >> 7;
  float sa = 0.f, sb = 0.f;
  const float* wrow = W1 + (size_t)k*256 + h*64;
  const float* as = a_src + h*64;
  const float* ad = a_dst + h*64;
  #pragma unroll 8
  for (int j = 0; j < 64; ++j) { sa += wrow[j]*as[j]; sb += wrow[j]*ad[j]; }
  w1a[k*4 + h] = sa;
  w1b[k*4 + h] = sb;
}

// ------------- w1t [256][128] fp16 = W1^T -------------
__global__ __launch_bounds__(256) void k_w1prep(
    const float* __restrict__ W1, _Float16* __restrict__ w1t) {
  int idx = blockIdx.x*256 + threadIdx.x;   // 32768
  int j = idx >> 7, k = idx & 127;
  w1t[idx] = (_Float16)W1[(size_t)k*256 + j];
}

// ------------- lx = logmap0(x) fp16 [N,128]; es1/ed1 [N,4] = lx @ w1a/w1b -------------
__global__ void k_lx_es(const float* __restrict__ x,
                        const float* __restrict__ w1a, const float* __restrict__ w1b,
                        _Float16* __restrict__ lxh,
                        float* __restrict__ es, float* __restrict__ ed, int N) {
  int tidg = blockIdx.x*blockDim.x + threadIdx.x;
  int wid = tidg >> 6, lane = tidg & 63;
  int nw = (gridDim.x * blockDim.x) >> 6;
  for (int row = wid; row < N; row += nw) {
    float2 v = *(const float2*)(x + (size_t)row*128 + lane*2);
    float ss = v.x*v.x + v.y*v.y;
    #pragma unroll
    for (int o = 32; o; o >>= 1) ss += __shfl_xor(ss, o);
    float n  = fmaxf(sqrtf(ss), EPSF);
    float nc = fminf(n, 1.f - 1e-5f);
    float sc = atanhf(nc) / n;                 // logmap0 scale
    float l0 = v.x*sc, l1 = v.y*sc;
    half2v hv; hv.x = (_Float16)l0; hv.y = (_Float16)l1;
    *(half2v*)(lxh + (size_t)row*128 + lane*2) = hv;
    float4 a0 = *(const float4*)(w1a + (lane*2)*4);
    float4 a1 = *(const float4*)(w1a + (lane*2+1)*4);
    float4 b0 = *(const float4*)(w1b + (lane*2)*4);
    float4 b1 = *(const float4*)(w1b + (lane*2+1)*4);
    float4 ps, pd;
    ps.x = l0*a0.x + l1*a1.x; ps.y = l0*a0.y + l1*a1.y;
    ps.z = l0*a0.z + l1*a1.z; ps.w = l0*a0.w + l1*a1.w;
    pd.x = l0*b0.x + l1*b1.x; pd.y = l0*b0.y + l1*b1.y;
    pd.z = l0*b0.z + l1*b1.z; pd.w = l0*b0.w + l1*b1.w;
    #pragma unroll
    for (int o = 32; o; o >>= 1) {
      ps.x += __shfl_xor(ps.x, o); ps.y += __shfl_xor(ps.y, o);
      ps.z += __shfl_xor(ps.z, o); ps.w += __shfl_xor(ps.w, o);
      pd.x += __shfl_xor(pd.x, o); pd.y += __shfl_xor(pd.y, o);
      pd.z += __shfl_xor(pd.z, o); pd.w += __shfl_xor(pd.w, o);
    }
    if (lane == 0) {
      *(float4*)(es + (size_t)row*4) = ps;
      *(float4*)(ed + (size_t)row*4) = pd;
    }
  }
}

// ------------- gemm1 via MFMA: h1 = lx @ W1 (fp16 in, f32 acc, fp16 out)
//   block = 32 rows, 4 waves: wave (rt=wv&1, ch=wv>>1); 8 col-tiles x 4 K-steps
#define LXP 136   // padded halves per lx row in LDS
#define H1P 264   // padded halves per h1 row in LDS
__global__ __launch_bounds__(256) void k_gemm1_mfma(
    const _Float16* __restrict__ lxh, const _Float16* __restrict__ w1t,
    _Float16* __restrict__ h1h, int N) {
  __shared__ _Float16 lxs[32*LXP];   // ~8.5 KB
  __shared__ _Float16 h1s[32*H1P];   // ~16.5 KB
  const int tid = threadIdx.x;
  const int block0 = blockIdx.x * 32;
  const int vrows = min(32, N - block0);
  // stage lx: 32 rows x 128 halves = 512 x 16B
  for (int i = tid; i < 512; i += 256) {
    int r = i >> 4, c = (i & 15) * 8;
    uint4 v = make_uint4(0u,0u,0u,0u);
    if (r < vrows) v = *(const uint4*)(lxh + (size_t)(block0 + r)*128 + c);
    *(uint4*)(lxs + r*LXP + c) = v;
  }
  __syncthreads();
  const int wv = tid >> 6, lane = tid & 63;
  const int rt = wv & 1;               // row-tile (16 rows)
  const int ch = wv >> 1;              // col-half (128 cols)
  const int arow = rt*16 + (lane & 15);
  const int koff = (lane >> 4) * 8;
  f32x4 acc[8];
  #pragma unroll
  for (int t = 0; t < 8; ++t) acc[t] = (f32x4){0.f,0.f,0.f,0.f};
  #pragma unroll
  for (int ks = 0; ks < 4; ++ks) {
    half8 a = *(const half8*)(lxs + arow*LXP + ks*32 + koff);
    #pragma unroll
    for (int t = 0; t < 8; ++t) {
      const int col0 = ch*128 + t*16;
      half8 b = *(const half8*)(w1t + (size_t)(col0 + (lane & 15))*128 + ks*32 + koff);
      acc[t] = __builtin_amdgcn_mfma_f32_16x16x32_f16(a, b, acc[t], 0, 0, 0);
    }
  }
  // D -> LDS (fp16): col = lane&15, row = (lane>>4)*4 + r  [HW-verified layout]
  #pragma unroll
  for (int t = 0; t < 8; ++t) {
    const int col = ch*128 + t*16 + (lane & 15);
    #pragma unroll
    for (int r = 0; r < 4; ++r) {
      const int row = rt*16 + (lane >> 4)*4 + r;
      h1s[row*H1P + col] = (_Float16)acc[t][r];
    }
  }
  __syncthreads();
  // coalesced store: 32 rows x 256 halves = 1024 x 16B
  for (int i = tid; i < 1024; i += 256) {
    int r = i >> 5, c = (i & 31) * 8;
    if (r < vrows) {
      uint4 v = *(const uint4*)(h1s + r*H1P + c);
      *(uint4*)(h1h + (size_t)(block0 + r)*256 + c) = v;
    }
  }
}

// ------------- layer1 aggregation: software-pipelined gather+FMA
//   wave per dst; lane owns cols lane*4..+3 (head = lane>>4); in-register wsum
__global__ void k_agg1_csr(const int* __restrict__ rowptr, const int* __restrict__ csrc,
                           const half4* __restrict__ w0,
                           const _Float16* __restrict__ h1h, _Float16* __restrict__ t2h,
                           int N) {
  int tidg = blockIdx.x*blockDim.x + threadIdx.x;
  int wid = tidg >> 6, lane = tidg & 63;
  int nw = (gridDim.x * blockDim.x) >> 6;
  const int h = lane >> 4;
  const _Float16* wp = (const _Float16*)w0;
  for (int d = wid; d < N; d += nw) {
    const int beg = rowptr[d], end = rowptr[d+1];
    float4 acc = make_float4(0.f,0.f,0.f,0.f);
    float wsum = 0.f;
    int k = beg;
    const int kend4 = beg + ((end - beg) & ~3);
    if (k < kend4) {
      int s0 = csrc[k], s1 = csrc[k+1], s2 = csrc[k+2], s3 = csrc[k+3];
      float wa = (float)wp[(size_t)(k+0)*4 + h];
      float wb = (float)wp[(size_t)(k+1)*4 + h];
      float wc = (float)wp[(size_t)(k+2)*4 + h];
      float wd = (float)wp[(size_t)(k+3)*4 + h];
      for (;;) {
        half4 v0 = *(const half4*)(h1h + (size_t)s0*256 + lane*4);
        half4 v1 = *(const half4*)(h1h + (size_t)s1*256 + lane*4);
        half4 v2 = *(const half4*)(h1h + (size_t)s2*256 + lane*4);
        half4 v3 = *(const half4*)(h1h + (size_t)s3*256 + lane*4);
        k += 4;
        const bool more = (k < kend4);
        int t0 = 0, t1 = 0, t2 = 0, t3 = 0;
        float ua = 0.f, ub = 0.f, uc = 0.f, ud = 0.f;
        if (more) {
          t0 = csrc[k]; t1 = csrc[k+1]; t2 = csrc[k+2]; t3 = csrc[k+3];
          ua = (float)wp[(size_t)(k+0)*4 + h];
          ub = (float)wp[(size_t)(k+1)*4 + h];
          uc = (float)wp[(size_t)(k+2)*4 + h];
          ud = (float)wp[(size_t)(k+3)*4 + h];
        }
        wsum += (wa + wb) + (wc + wd);
        acc.x += wa*(float)v0.x + wb*(float)v1.x + wc*(float)v2.x + wd*(float)v3.x;
        acc.y += wa*(float)v0.y + wb*(float)v1.y + wc*(float)v2.y + wd*(float)v3.y;
        acc.z += wa*(float)v0.z + wb*(float)v1.z + wc*(float)v2.z + wd*(float)v3.z;
        acc.w += wa*(float)v0.w + wb*(float)v1.w + wc*(float)v2.w + wd*(float)v3.w;
        if (!more) break;
        s0 = t0; s1 = t1; s2 = t2; s3 = t3;
        wa = ua; wb = ub; wc = uc; wd = ud;
      }
    }
    for (; k < end; ++k) {
      int s = csrc[k];
      float wa = (float)wp[(size_t)k*4 + h];
      half4 hv = *(const half4*)(h1h + (size_t)s*256 + lane*4);
      wsum += wa;
      acc.x += wa*(float)hv.x; acc.y += wa*(float)hv.y;
      acc.z += wa*(float)hv.z; acc.w += wa*(float)hv.w;
    }
    float inv = 1.f / (wsum + 1e-16f);
    float ax = acc.x*inv, ay = acc.y*inv, az = acc.z*inv, aw = acc.w*inv;
    float ss = ax*ax + ay*ay + az*az + aw*aw;
    #pragma unroll
    for (int o = 32; o; o >>= 1) ss += __shfl_xor(ss, o);
    float n  = fmaxf(sqrtf(ss), EPSF);
    float s1 = tanhf(n) / n;                    // expmap0 scale
    float n2 = fmaxf(s1 * n, EPSF);             // = tanh(n), clamped
    float nc = fminf(n2, 1.f - 1e-5f);
    float sc = s1 * atanhf(nc) / n2;
    half4 o4; o4.x = (_Float16)(ax*sc); o4.y = (_Float16)(ay*sc);
              o4.z = (_Float16)(az*sc); o4.w = (_Float16)(aw*sc);
    *(half4*)(t2h + (size_t)d*256 + lane*4) = o4;
  }
}

// ------------- layer2: t2h (fp16) [N,256] @ W2 [256,64] -> h2 (fp16); es2/ed2 [N]
#define T2PAD 260
__global__ __launch_bounds__(256) void k_gemm2(
    const _Float16* __restrict__ t2h, const float* __restrict__ W2,
    const float* __restrict__ a_src, const float* __restrict__ a_dst,
    _Float16* __restrict__ h2h, float* __restrict__ es, float* __restrict__ ed, int N) {
  __shared__ float tile[32*T2PAD];
  const int tid = threadIdx.x;
  const int block0 = blockIdx.x * 32;
  int validq = (block0 < N ? ((N - block0 < 32) ? (N - block0) : 32) : 0) * 64;
  const half4* srcp = (const half4*)(t2h + (size_t)block0 * 256);
  #pragma unroll
  for (int i0 = 0; i0 < 2048; i0 += 256) {
    int i = i0 + tid;
    half4 v; v.x = v.y = v.z = v.w = (_Float16)0.f;
    if (i < validq) v = srcp[i];
    int r = i >> 6, c = (i & 63) * 4;
    *(float4*)&tile[r*T2PAD + c] =
        make_float4((float)v.x, (float)v.y, (float)v.z, (float)v.w);
  }
  __syncthreads();
  const int wv = tid >> 6, lane = tid & 63;
  const int jj = (lane & 15) * 4;
  const int rg = lane >> 4;
  const int rbase = wv*8 + rg*2;
  float4 acc[2];
  acc[0] = make_float4(0.f,0.f,0.f,0.f);
  acc[1] = make_float4(0.f,0.f,0.f,0.f);
  for (int k = 0; k < 256; k += 4) {
    float4 w0 = *(const float4*)(W2 + (size_t)(k+0)*64 + jj);
    float4 w1 = *(const float4*)(W2 + (size_t)(k+1)*64 + jj);
    float4 w2 = *(const float4*)(W2 + (size_t)(k+2)*64 + jj);
    float4 w3 = *(const float4*)(W2 + (size_t)(k+3)*64 + jj);
    #pragma unroll
    for (int rr = 0; rr < 2; ++rr) {
      float4 tv = *(const float4*)&tile[(rbase + rr)*T2PAD + k];
      acc[rr].x += tv.x*w0.x + tv.y*w1.x + tv.z*w2.x + tv.w*w3.x;
      acc[rr].y += tv.x*w0.y + tv.y*w1.y + tv.z*w2.y + tv.w*w3.y;
      acc[rr].z += tv.x*w0.z + tv.y*w1.z + tv.z*w2.z + tv.w*w3.z;
      acc[rr].w += tv.x*w0.w + tv.y*w1.w + tv.z*w2.w + tv.w*w3.w;
    }
  }
  const float4 as4 = *(const float4*)(a_src + jj);
  const float4 ad4 = *(const float4*)(a_dst + jj);
  #pragma unroll
  for (int rr = 0; rr < 2; ++rr) {
    int row = block0 + rbase + rr;
    if (row < N) {
      float4 a = acc[rr];
      half4 hv; hv.x = (_Float16)a.x; hv.y = (_Float16)a.y;
                hv.z = (_Float16)a.z; hv.w = (_Float16)a.w;
      *(half4*)(h2h + (size_t)row*64 + jj) = hv;
      float ps = a.x*as4.x + a.y*as4.y + a.z*as4.z + a.w*as4.w;
      float pd = a.x*ad4.x + a.y*ad4.y + a.z*ad4.z + a.w*ad4.w;
      #pragma unroll
      for (int o = 8; o; o >>= 1) { ps += __shfl_xor(ps, o); pd += __shfl_xor(pd, o); }
      if ((lane & 15) == 0) { es[row] = ps; ed[row] = pd; }
    }
  }
}

// ------------- layer2 aggregation (CSR, wave per dst, pipelined) + fused expmap0 ---------
__global__ void k_agg2_csr(const int* __restrict__ rowptr, const int* __restrict__ csrc,
                           const float* __restrict__ es, const float* __restrict__ ed,
                           const _Float16* __restrict__ h2h, float* __restrict__ out, int N) {
  int tidg = blockIdx.x*blockDim.x + threadIdx.x;
  int wid = tidg >> 6, lane = tidg & 63;
  int nw = (gridDim.x * blockDim.x) >> 6;
  for (int d = wid; d < N; d += nw) {
    const int beg = rowptr[d], end = rowptr[d+1];
    const float edv = ed[d];
    float acc = 0.f, wsum = 0.f;
    int k = beg;
    const int kend4 = beg + ((end - beg) & ~3);
    if (k < kend4) {
      int s0 = csrc[k], s1 = csrc[k+1], s2 = csrc[k+2], s3 = csrc[k+3];
      for (;;) {
        float e0 = es[s0], e1 = es[s1], e2 = es[s2], e3 = es[s3];
        float x0 = (float)h2h[(size_t)s0*64 + lane];
        float x1 = (float)h2h[(size_t)s1*64 + lane];
        float x2 = (float)h2h[(size_t)s2*64 + lane];
        float x3 = (float)h2h[(size_t)s3*64 + lane];
        k += 4;
        const bool more = (k < kend4);
        int t0 = 0, t1 = 0, t2 = 0, t3 = 0;
        if (more) { t0 = csrc[k]; t1 = csrc[k+1]; t2 = csrc[k+2]; t3 = csrc[k+3]; }
        float w0 = __expf(lrelu02(e0 + edv));
        float w1 = __expf(lrelu02(e1 + edv));
        float w2 = __expf(lrelu02(e2 + edv));
        float w3 = __expf(lrelu02(e3 + edv));
        wsum += (w0 + w1) + (w2 + w3);
        acc += w0*x0 + w1*x1 + w2*x2 + w3*x3;
        if (!more) break;
        s0 = t0; s1 = t1; s2 = t2; s3 = t3;
      }
    }
    for (; k < end; ++k) {
      int s = csrc[k];
      float w = __expf(lrelu02(es[s] + edv));
      wsum += w;
      acc += w * (float)h2h[(size_t)s*64 + lane];
    }
    float a = acc / (wsum + 1e-16f);
    float ss = a*a;
    #pragma unroll
    for (int o = 32; o; o >>= 1) ss += __shfl_xor(ss, o);
    float n  = fmaxf(sqrtf(ss), EPSF);
    float sc = tanhf(n) / n;                    // expmap0 scale
    out[(size_t)d*64 + lane] = a * sc;
  }
}

extern "C" void kernel_launch(void* const* d_in, const int* in_sizes, int n_in,
                              void* d_out, int out_size, void* d_ws, size_t ws_size,
                              hipStream_t stream) {
  const float* x      = (const float*)d_in[0];
  const float* W1     = (const float*)d_in[1];
  const float* a_src1 = (const float*)d_in[2];
  const float* a_dst1 = (const float*)d_in[3];
  const float* W2     = (const float*)d_in[4];
  const float* a_src2 = (const float*)d_in[5];
  const float* a_dst2 = (const float*)d_in[6];
  const int*   ei0    = (const int*)d_in[7];
  const int*   ei1    = (const int*)d_in[8];
  const int N  = in_sizes[0] / 128;
  const int E0 = in_sizes[7] / 2;
  const int E1 = in_sizes[8] / 2;
  const int* src0 = ei0;  const int* dst0 = ei0 + E0;
  const int* src1 = ei1;  const int* dst1 = ei1 + E1;
  float* out = (float*)d_out;
  const int nb = (N + 127) >> 7;

  float* ws = (float*)d_ws;
  size_t o = 0;
  float* es1   = ws + o; o += (size_t)N*4;
  float* ed1   = ws + o; o += (size_t)N*4;
  float* es2   = ws + o; o += (size_t)N;
  float* ed2   = ws + o; o += (size_t)N;
  float* w1a   = ws + o; o += 512;
  float* w1b   = ws + o; o += 512;
  _Float16* lxh = (_Float16*)(ws + o); o += (size_t)N*64;   // N*128 halves
  _Float16* w1t = (_Float16*)(ws + o); o += 16384;          // 32768 halves
  _Float16* h1h = (_Float16*)(ws + o); o += (size_t)N*128;  // N*256 halves
  _Float16* t2h = (_Float16*)(ws + o); o += (size_t)N*128;  // N*256 halves
  _Float16* h2h = (_Float16*)(ws + o); o += (size_t)N*32;   // N*64 halves
  o += (o & 1);                                             // 8B align
  half4* w0    = (half4*)(ws + o); o += (size_t)E0*2;       // E0*4 halves
  u64* temp0 = (u64*)(ws + o); o += (size_t)E0*2;
  u64* temp1 = (u64*)(ws + o); o += (size_t)E1*2;
  int* iws = (int*)(ws + o);
  size_t io = 0;
  int* rowptr0 = iws + io; io += N + 1;
  int* rowptr1 = iws + io; io += N + 1;
  int* bcnt0   = iws + io; io += NBMAX;  // bcnt0/bcnt1 adjacent: one memset
  int* bcnt1   = iws + io; io += NBMAX;
  int* bbase0  = iws + io; io += NBMAX + 1;
  int* bbase1  = iws + io; io += NBMAX + 1;
  int* bcur0   = iws + io; io += NBMAX;
  int* bcur1   = iws + io; io += NBMAX;
  int* csrc0   = iws + io; io += E0;
  int* csrc1   = iws + io; io += E1;

  dim3 blk(256);
  const int blocksA0 = (E0 + 4095) / 4096;
  const int blocksA1 = (E1 + 4095) / 4096;
  hipMemsetAsync(bcnt0, 0, 2*NBMAX*sizeof(int), stream);
  // precompute: w1a/w1b, W1^T fp16, lx + es1/ed1 (bucketB2 consumes es1/ed1)
  k_w1ab   <<<1, 512, 0, stream>>>(W1, a_src1, a_dst1, w1a, w1b);
  k_w1prep <<<128, blk, 0, stream>>>(W1, w1t);
  k_lx_es  <<<2048, blk, 0, stream>>>(x, w1a, w1b, lxh, es1, ed1, N);
  // CSR build (+ graph-0 edge weights fused into bucketB2)
  k_bhist  <<<1024, blk, 0, stream>>>(dst0, E0, dst1, E1, bcnt0, bcnt1, nb);
  k_bscan  <<<1, 1024, 0, stream>>>(bcnt0, bbase0, bcur0, bcnt1, bbase1, bcur1, nb);
  k_bucketA<<<blocksA0 + blocksA1, blk, 0, stream>>>(
      src0, dst0, bcur0, temp0, E0, blocksA0, src1, dst1, bcur1, temp1, E1, nb);
  k_bucketB2<<<2*nb, blk, 0, stream>>>(temp0, bbase0, rowptr0, csrc0,
                                       es1, ed1, w0,
                                       temp1, bbase1, rowptr1, csrc1, N, nb);
  // layer-1 GEMM on matrix cores
  k_gemm1_mfma<<<(N+31)/32, blk, 0, stream>>>(lxh, w1t, h1h, N);
  // layer-1 aggregation (pipelined gather) + fused maps -> t2h
  k_agg1_csr<<<2048, blk, 0, stream>>>(rowptr0, csrc0, w0, h1h, t2h, N);
  // layer 2
  k_gemm2  <<<(N+31)/32, blk, 0, stream>>>(t2h, W2, a_src2, a_dst2, h2h, es2, ed2, N);
  k_agg2_csr<<<2048, blk, 0, stream>>>(rowptr1, csrc1, es2, ed2, h2h, out, N);
}

// Round 23
// 290.217 us; speedup vs baseline: 1.1141x; 1.1141x over previous
//
#include <hip/hip_runtime.h>

#define EPSF 1e-7f
#define NBMAX 512   // max dst-buckets (ceil(N/128)); N=50000 -> 391

typedef __attribute__((ext_vector_type(4))) _Float16 half4;
typedef __attribute__((ext_vector_type(8))) _Float16 half8;
typedef __attribute__((ext_vector_type(2))) _Float16 half2v;
typedef __attribute__((ext_vector_type(4))) float f32x4;
typedef unsigned long long u64;

__device__ __forceinline__ float lrelu02(float x){ return x > 0.f ? x : 0.2f*x; }

// ---------------- CSR build (bucket-local, no N-sized scan) ----------------
__global__ __launch_bounds__(256) void k_bhist(
    const int* __restrict__ dst0, int E0, const int* __restrict__ dst1, int E1,
    int* __restrict__ bcnt0, int* __restrict__ bcnt1, int nb) {
  __shared__ int h0[NBMAX], h1[NBMAX];
  const int tid = threadIdx.x;
  const int g = blockIdx.x*blockDim.x + tid;
  const int stride = gridDim.x*blockDim.x;
  for (int i = tid; i < nb; i += 256) { h0[i] = 0; h1[i] = 0; }
  __syncthreads();
  for (int i = g; i < E0; i += stride) atomicAdd(&h0[dst0[i] >> 7], 1);
  for (int i = g; i < E1; i += stride) atomicAdd(&h1[dst1[i] >> 7], 1);
  __syncthreads();
  for (int i = tid; i < nb; i += 256) {
    if (h0[i]) atomicAdd(&bcnt0[i], h0[i]);
    if (h1[i]) atomicAdd(&bcnt1[i], h1[i]);
  }
}

__global__ __launch_bounds__(1024) void k_bscan(
    const int* __restrict__ bcnt0, int* __restrict__ bbase0, int* __restrict__ bcur0,
    const int* __restrict__ bcnt1, int* __restrict__ bbase1, int* __restrict__ bcur1,
    int nb) {
  __shared__ int wt[16];
  const int tid = threadIdx.x;
  const int half = tid >> 9, idx = tid & 511;
  const int* bcnt = half ? bcnt1 : bcnt0;
  int* bbase = half ? bbase1 : bbase0;
  int* bcur  = half ? bcur1  : bcur0;
  int v = (idx < nb) ? bcnt[idx] : 0;
  const int lane = tid & 63, w = tid >> 6;
  int inc = v;
  #pragma unroll
  for (int o = 1; o < 64; o <<= 1) { int t = __shfl_up(inc, o); if (lane >= o) inc += t; }
  if (lane == 63) wt[w] = inc;
  __syncthreads();
  int woff = 0;
  for (int i = half*8; i < w; ++i) woff += wt[i];
  int excl = woff + inc - v;
  if (idx < nb) { bbase[idx] = excl; bcur[idx] = excl; }
  if (idx == nb-1) bbase[nb] = excl + v;
}

__global__ __launch_bounds__(256) void k_bucketA(
    const int* __restrict__ src0, const int* __restrict__ dst0,
    int* __restrict__ bcur0, u64* __restrict__ temp0, int E0, int blocksA0,
    const int* __restrict__ src1, const int* __restrict__ dst1,
    int* __restrict__ bcur1, u64* __restrict__ temp1, int E1, int nb) {
  const int g0 = (blockIdx.x < blocksA0);
  const int* src = g0 ? src0 : src1;
  const int* dst = g0 ? dst0 : dst1;
  int* bcur      = g0 ? bcur0 : bcur1;
  u64* temp      = g0 ? temp0 : temp1;
  const int E    = g0 ? E0 : E1;
  const int cb   = g0 ? blockIdx.x : blockIdx.x - blocksA0;
  __shared__ int hist[NBMAX];
  __shared__ int lbase[NBMAX];
  const int tid = threadIdx.x;
  const int chunk0 = cb * 4096;
  const int e_end = min(chunk0 + 4096, E);
  for (int i = tid; i < nb; i += 256) hist[i] = 0;
  __syncthreads();
  for (int i = chunk0 + tid; i < e_end; i += 256)
    atomicAdd(&hist[dst[i] >> 7], 1);
  __syncthreads();
  for (int bn = tid; bn < nb; bn += 256) {
    int c = hist[bn];
    lbase[bn] = c ? atomicAdd(&bcur[bn], c) : 0;
    hist[bn] = 0;
  }
  __syncthreads();
  for (int i = chunk0 + tid; i < e_end; i += 256) {
    int d = dst[i];
    int bn = d >> 7;
    int off = atomicAdd(&hist[bn], 1);
    temp[(size_t)lbase[bn] + off] = ((u64)(unsigned)d << 32) | (unsigned)src[i];
  }
}

// pass B: per bucket, per-dst count + local scan -> rowptr; scatter csrc.
// For graph 0 additionally: per-edge attention weights (fp16).
__global__ __launch_bounds__(256) void k_bucketB2(
    const u64* __restrict__ temp0, const int* __restrict__ bbase0,
    int* __restrict__ rowptr0, int* __restrict__ csrc0,
    const float* __restrict__ es1, const float* __restrict__ ed1,
    half4* __restrict__ w0,
    const u64* __restrict__ temp1, const int* __restrict__ bbase1,
    int* __restrict__ rowptr1, int* __restrict__ csrc1, int N, int nb) {
  const int g0 = (blockIdx.x < nb);
  const u64* temp = g0 ? temp0 : temp1;
  const int* bbase = g0 ? bbase0 : bbase1;
  int* rowptr = g0 ? rowptr0 : rowptr1;
  int* csrc   = g0 ? csrc0 : csrc1;
  const int b = g0 ? blockIdx.x : blockIdx.x - nb;
  __shared__ int lcnt[128];
  __shared__ int lcur[128];
  __shared__ int wt4[4];
  __shared__ float ledv[512];
  const int tid = threadIdx.x;
  const int d0 = b << 7;
  const int d1 = min(d0 + 128, N);
  const int lo = bbase[b], hi = bbase[b+1];
  if (tid < 128) lcnt[tid] = 0;
  if (g0) {
    for (int i = tid; i < (d1 - d0)*4; i += 256) ledv[i] = ed1[d0*4 + i];
  }
  __syncthreads();
  for (int k = lo + tid; k < hi; k += 256)
    atomicAdd(&lcnt[(int)(temp[k] >> 32) - d0], 1);
  __syncthreads();
  int v = (tid < 128) ? lcnt[tid] : 0;
  const int lane = tid & 63, w = tid >> 6;
  int inc = v;
  #pragma unroll
  for (int o = 1; o < 64; o <<= 1) { int t = __shfl_up(inc, o); if (lane >= o) inc += t; }
  if (lane == 63) wt4[w] = inc;
  __syncthreads();
  int woff = 0;
  for (int i = 0; i < w; ++i) woff += wt4[i];
  int excl = lo + woff + inc - v;
  if (tid < d1 - d0) { rowptr[d0 + tid] = excl; lcur[tid] = excl; }
  if (b == nb-1 && tid == 0) rowptr[N] = hi;
  __syncthreads();
  for (int k = lo + tid; k < hi; k += 256) {
    u64 p = temp[k];
    int d = (int)(p >> 32);
    int s = (int)(unsigned)p;
    int pos = atomicAdd(&lcur[d - d0], 1);
    csrc[pos] = s;
    if (g0) {
      float4 e = *(const float4*)(es1 + (size_t)s*4);
      int ld = (d - d0)*4;
      half4 wh;
      wh.x = (_Float16)__expf(lrelu02(e.x + ledv[ld+0]));
      wh.y = (_Float16)__expf(lrelu02(e.y + ledv[ld+1]));
      wh.z = (_Float16)__expf(lrelu02(e.z + ledv[ld+2]));
      wh.w = (_Float16)__expf(lrelu02(e.w + ledv[ld+3]));
      w0[pos] = wh;
    }
  }
}

// ------------- w1a/w1b [128][4]: w1a[k][h] = sum_j W1[k][h*64+j]*a_src[h][j] -------------
__global__ __launch_bounds__(512) void k_w1ab(
    const float* __restrict__ W1, const float* __restrict__ a_src,
    const float* __restrict__ a_dst, float* __restrict__ w1a, float* __restrict__ w1b) {
  const int t = threadIdx.x;
  const int k = t & 127, h = t >> 7;
  float sa = 0.f, sb = 0.f;
  const float* wrow = W1 + (size_t)k*256 + h*64;
  const float* as = a_src + h*64;
  const float* ad = a_dst + h*64;
  #pragma unroll 8
  for (int j = 0; j < 64; ++j) { sa += wrow[j]*as[j]; sb += wrow[j]*ad[j]; }
  w1a[k*4 + h] = sa;
  w1b[k*4 + h] = sb;
}

// ------------- w1t [256][128] fp16 = W1^T -------------
__global__ __launch_bounds__(256) void k_w1prep(
    const float* __restrict__ W1, _Float16* __restrict__ w1t) {
  int idx = blockIdx.x*256 + threadIdx.x;   // 32768
  int j = idx >> 7, k = idx & 127;
  w1t[idx] = (_Float16)W1[(size_t)k*256 + j];
}

// ------------- w2t [64][256] fp16 = W2^T -------------
__global__ __launch_bounds__(256) void k_w2prep(
    const float* __restrict__ W2, _Float16* __restrict__ w2t) {
  int idx = blockIdx.x*256 + threadIdx.x;   // 16384
  int j = idx >> 8, k = idx & 255;
  w2t[idx] = (_Float16)W2[(size_t)k*64 + j];
}

// ------------- lx = logmap0(x) fp16 [N,128]; es1/ed1 [N,4] = lx @ w1a/w1b -------------
__global__ void k_lx_es(const float* __restrict__ x,
                        const float* __restrict__ w1a, const float* __restrict__ w1b,
                        _Float16* __restrict__ lxh,
                        float* __restrict__ es, float* __restrict__ ed, int N) {
  int tidg = blockIdx.x*blockDim.x + threadIdx.x;
  int wid = tidg >> 6, lane = tidg & 63;
  int nw = (gridDim.x * blockDim.x) >> 6;
  for (int row = wid; row < N; row += nw) {
    float2 v = *(const float2*)(x + (size_t)row*128 + lane*2);
    float ss = v.x*v.x + v.y*v.y;
    #pragma unroll
    for (int o = 32; o; o >>= 1) ss += __shfl_xor(ss, o);
    float n  = fmaxf(sqrtf(ss), EPSF);
    float nc = fminf(n, 1.f - 1e-5f);
    float sc = atanhf(nc) / n;                 // logmap0 scale
    float l0 = v.x*sc, l1 = v.y*sc;
    half2v hv; hv.x = (_Float16)l0; hv.y = (_Float16)l1;
    *(half2v*)(lxh + (size_t)row*128 + lane*2) = hv;
    float4 a0 = *(const float4*)(w1a + (lane*2)*4);
    float4 a1 = *(const float4*)(w1a + (lane*2+1)*4);
    float4 b0 = *(const float4*)(w1b + (lane*2)*4);
    float4 b1 = *(const float4*)(w1b + (lane*2+1)*4);
    float4 ps, pd;
    ps.x = l0*a0.x + l1*a1.x; ps.y = l0*a0.y + l1*a1.y;
    ps.z = l0*a0.z + l1*a1.z; ps.w = l0*a0.w + l1*a1.w;
    pd.x = l0*b0.x + l1*b1.x; pd.y = l0*b0.y + l1*b1.y;
    pd.z = l0*b0.z + l1*b1.z; pd.w = l0*b0.w + l1*b1.w;
    #pragma unroll
    for (int o = 32; o; o >>= 1) {
      ps.x += __shfl_xor(ps.x, o); ps.y += __shfl_xor(ps.y, o);
      ps.z += __shfl_xor(ps.z, o); ps.w += __shfl_xor(ps.w, o);
      pd.x += __shfl_xor(pd.x, o); pd.y += __shfl_xor(pd.y, o);
      pd.z += __shfl_xor(pd.z, o); pd.w += __shfl_xor(pd.w, o);
    }
    if (lane == 0) {
      *(float4*)(es + (size_t)row*4) = ps;
      *(float4*)(ed + (size_t)row*4) = pd;
    }
  }
}

// ------------- gemm1 via MFMA: h1 = lx @ W1 (fp16 in, f32 acc, fp16 out)
#define LXP 136   // padded halves per lx row in LDS
#define H1P 264   // padded halves per h1 row in LDS
__global__ __launch_bounds__(256) void k_gemm1_mfma(
    const _Float16* __restrict__ lxh, const _Float16* __restrict__ w1t,
    _Float16* __restrict__ h1h, int N) {
  __shared__ _Float16 lxs[32*LXP];   // ~8.5 KB
  __shared__ _Float16 h1s[32*H1P];   // ~16.5 KB
  const int tid = threadIdx.x;
  const int block0 = blockIdx.x * 32;
  const int vrows = min(32, N - block0);
  for (int i = tid; i < 512; i += 256) {
    int r = i >> 4, c = (i & 15) * 8;
    uint4 v = make_uint4(0u,0u,0u,0u);
    if (r < vrows) v = *(const uint4*)(lxh + (size_t)(block0 + r)*128 + c);
    *(uint4*)(lxs + r*LXP + c) = v;
  }
  __syncthreads();
  const int wv = tid >> 6, lane = tid & 63;
  const int rt = wv & 1;               // row-tile (16 rows)
  const int ch = wv >> 1;              // col-half (128 cols)
  const int arow = rt*16 + (lane & 15);
  const int koff = (lane >> 4) * 8;
  f32x4 acc[8];
  #pragma unroll
  for (int t = 0; t < 8; ++t) acc[t] = (f32x4){0.f,0.f,0.f,0.f};
  #pragma unroll
  for (int ks = 0; ks < 4; ++ks) {
    half8 a = *(const half8*)(lxs + arow*LXP + ks*32 + koff);
    #pragma unroll
    for (int t = 0; t < 8; ++t) {
      const int col0 = ch*128 + t*16;
      half8 b = *(const half8*)(w1t + (size_t)(col0 + (lane & 15))*128 + ks*32 + koff);
      acc[t] = __builtin_amdgcn_mfma_f32_16x16x32_f16(a, b, acc[t], 0, 0, 0);
    }
  }
  #pragma unroll
  for (int t = 0; t < 8; ++t) {
    const int col = ch*128 + t*16 + (lane & 15);
    #pragma unroll
    for (int r = 0; r < 4; ++r) {
      const int row = rt*16 + (lane >> 4)*4 + r;
      h1s[row*H1P + col] = (_Float16)acc[t][r];
    }
  }
  __syncthreads();
  for (int i = tid; i < 1024; i += 256) {
    int r = i >> 5, c = (i & 31) * 8;
    if (r < vrows) {
      uint4 v = *(const uint4*)(h1s + r*H1P + c);
      *(uint4*)(h1h + (size_t)(block0 + r)*256 + c) = v;
    }
  }
}

// ------------- layer1 aggregation: software-pipelined gather+FMA -------------
__global__ void k_agg1_csr(const int* __restrict__ rowptr, const int* __restrict__ csrc,
                           const half4* __restrict__ w0,
                           const _Float16* __restrict__ h1h, _Float16* __restrict__ t2h,
                           int N) {
  int tidg = blockIdx.x*blockDim.x + threadIdx.x;
  int wid = tidg >> 6, lane = tidg & 63;
  int nw = (gridDim.x * blockDim.x) >> 6;
  const int h = lane >> 4;
  const _Float16* wp = (const _Float16*)w0;
  for (int d = wid; d < N; d += nw) {
    const int beg = rowptr[d], end = rowptr[d+1];
    float4 acc = make_float4(0.f,0.f,0.f,0.f);
    float wsum = 0.f;
    int k = beg;
    const int kend4 = beg + ((end - beg) & ~3);
    if (k < kend4) {
      int s0 = csrc[k], s1 = csrc[k+1], s2 = csrc[k+2], s3 = csrc[k+3];
      float wa = (float)wp[(size_t)(k+0)*4 + h];
      float wb = (float)wp[(size_t)(k+1)*4 + h];
      float wc = (float)wp[(size_t)(k+2)*4 + h];
      float wd = (float)wp[(size_t)(k+3)*4 + h];
      for (;;) {
        half4 v0 = *(const half4*)(h1h + (size_t)s0*256 + lane*4);
        half4 v1 = *(const half4*)(h1h + (size_t)s1*256 + lane*4);
        half4 v2 = *(const half4*)(h1h + (size_t)s2*256 + lane*4);
        half4 v3 = *(const half4*)(h1h + (size_t)s3*256 + lane*4);
        k += 4;
        const bool more = (k < kend4);
        int t0 = 0, t1 = 0, t2 = 0, t3 = 0;
        float ua = 0.f, ub = 0.f, uc = 0.f, ud = 0.f;
        if (more) {
          t0 = csrc[k]; t1 = csrc[k+1]; t2 = csrc[k+2]; t3 = csrc[k+3];
          ua = (float)wp[(size_t)(k+0)*4 + h];
          ub = (float)wp[(size_t)(k+1)*4 + h];
          uc = (float)wp[(size_t)(k+2)*4 + h];
          ud = (float)wp[(size_t)(k+3)*4 + h];
        }
        wsum += (wa + wb) + (wc + wd);
        acc.x += wa*(float)v0.x + wb*(float)v1.x + wc*(float)v2.x + wd*(float)v3.x;
        acc.y += wa*(float)v0.y + wb*(float)v1.y + wc*(float)v2.y + wd*(float)v3.y;
        acc.z += wa*(float)v0.z + wb*(float)v1.z + wc*(float)v2.z + wd*(float)v3.z;
        acc.w += wa*(float)v0.w + wb*(float)v1.w + wc*(float)v2.w + wd*(float)v3.w;
        if (!more) break;
        s0 = t0; s1 = t1; s2 = t2; s3 = t3;
        wa = ua; wb = ub; wc = uc; wd = ud;
      }
    }
    for (; k < end; ++k) {
      int s = csrc[k];
      float wa = (float)wp[(size_t)k*4 + h];
      half4 hv = *(const half4*)(h1h + (size_t)s*256 + lane*4);
      wsum += wa;
      acc.x += wa*(float)hv.x; acc.y += wa*(float)hv.y;
      acc.z += wa*(float)hv.z; acc.w += wa*(float)hv.w;
    }
    float inv = 1.f / (wsum + 1e-16f);
    float ax = acc.x*inv, ay = acc.y*inv, az = acc.z*inv, aw = acc.w*inv;
    float ss = ax*ax + ay*ay + az*az + aw*aw;
    #pragma unroll
    for (int o = 32; o; o >>= 1) ss += __shfl_xor(ss, o);
    float n  = fmaxf(sqrtf(ss), EPSF);
    float s1 = tanhf(n) / n;                    // expmap0 scale
    float n2 = fmaxf(s1 * n, EPSF);             // = tanh(n), clamped
    float nc = fminf(n2, 1.f - 1e-5f);
    float sc = s1 * atanhf(nc) / n2;
    half4 o4; o4.x = (_Float16)(ax*sc); o4.y = (_Float16)(ay*sc);
              o4.z = (_Float16)(az*sc); o4.w = (_Float16)(aw*sc);
    *(half4*)(t2h + (size_t)d*256 + lane*4) = o4;
  }
}

// ------------- gemm2 via MFMA: h2 = t2 @ W2 (fp16 in, f32 acc); es2/ed2 epilogue
#define T2SP 264  // padded halves per t2 row in LDS
#define H2SP 72   // padded halves per h2 row in LDS
__global__ __launch_bounds__(256) void k_gemm2_mfma(
    const _Float16* __restrict__ t2h, const _Float16* __restrict__ w2t,
    const float* __restrict__ a_src, const float* __restrict__ a_dst,
    _Float16* __restrict__ h2h, float* __restrict__ es, float* __restrict__ ed, int N) {
  __shared__ _Float16 t2s[32*T2SP];  // ~16.9 KB
  __shared__ _Float16 h2s[32*H2SP];  // ~4.6 KB
  const int tid = threadIdx.x;
  const int block0 = blockIdx.x * 32;
  const int vrows = min(32, N - block0);
  // stage t2: 32 rows x 256 halves = 1024 x 16B
  for (int i = tid; i < 1024; i += 256) {
    int r = i >> 5, c = (i & 31) * 8;
    uint4 v = make_uint4(0u,0u,0u,0u);
    if (r < vrows) v = *(const uint4*)(t2h + (size_t)(block0 + r)*256 + c);
    *(uint4*)(t2s + r*T2SP + c) = v;
  }
  __syncthreads();
  const int wv = tid >> 6, lane = tid & 63;
  const int rt = wv & 1;               // row-tile (16 rows)
  const int ch = wv >> 1;              // col-pair: cols ch*32..+31
  const int arow = rt*16 + (lane & 15);
  const int koff = (lane >> 4) * 8;
  f32x4 acc[2];
  acc[0] = (f32x4){0.f,0.f,0.f,0.f};
  acc[1] = (f32x4){0.f,0.f,0.f,0.f};
  #pragma unroll
  for (int ks = 0; ks < 8; ++ks) {
    half8 a = *(const half8*)(t2s + arow*T2SP + ks*32 + koff);
    #pragma unroll
    for (int t = 0; t < 2; ++t) {
      const int col0 = ch*32 + t*16;
      half8 b = *(const half8*)(w2t + (size_t)(col0 + (lane & 15))*256 + ks*32 + koff);
      acc[t] = __builtin_amdgcn_mfma_f32_16x16x32_f16(a, b, acc[t], 0, 0, 0);
    }
  }
  // D -> LDS: col = lane&15, row = (lane>>4)*4 + r
  #pragma unroll
  for (int t = 0; t < 2; ++t) {
    const int col = ch*32 + t*16 + (lane & 15);
    #pragma unroll
    for (int r = 0; r < 4; ++r) {
      const int row = rt*16 + (lane >> 4)*4 + r;
      h2s[row*H2SP + col] = (_Float16)acc[t][r];
    }
  }
  __syncthreads();
  // coalesced store: 32 rows x 64 halves = 256 x 16B
  {
    int i = tid;
    int r = i >> 3, c = (i & 7) * 8;
    if (r < vrows) {
      uint4 v = *(const uint4*)(h2s + r*H2SP + c);
      *(uint4*)(h2h + (size_t)(block0 + r)*64 + c) = v;
    }
  }
  // es2/ed2: 16-lane group owns rows rbase..rbase+1, lane owns cols jj..jj+3
  const int jj = (lane & 15) * 4;
  const int rg = lane >> 4;
  const int rbase = wv*8 + rg*2;
  const float4 as4 = *(const float4*)(a_src + jj);
  const float4 ad4 = *(const float4*)(a_dst + jj);
  #pragma unroll
  for (int rr = 0; rr < 2; ++rr) {
    int row = block0 + rbase + rr;
    if (row < N) {
      half4 hv = *(const half4*)(h2s + (rbase + rr)*H2SP + jj);
      float ax = (float)hv.x, ay = (float)hv.y, az = (float)hv.z, aw = (float)hv.w;
      float ps = ax*as4.x + ay*as4.y + az*as4.z + aw*as4.w;
      float pd = ax*ad4.x + ay*ad4.y + az*ad4.z + aw*ad4.w;
      #pragma unroll
      for (int o = 8; o; o >>= 1) { ps += __shfl_xor(ps, o); pd += __shfl_xor(pd, o); }
      if ((lane & 15) == 0) { es[row] = ps; ed[row] = pd; }
    }
  }
}

// ------------- layer2 aggregation (CSR, wave per dst, pipelined) + fused expmap0 ---------
__global__ void k_agg2_csr(const int* __restrict__ rowptr, const int* __restrict__ csrc,
                           const float* __restrict__ es, const float* __restrict__ ed,
                           const _Float16* __restrict__ h2h, float* __restrict__ out, int N) {
  int tidg = blockIdx.x*blockDim.x + threadIdx.x;
  int wid = tidg >> 6, lane = tidg & 63;
  int nw = (gridDim.x * blockDim.x) >> 6;
  for (int d = wid; d < N; d += nw) {
    const int beg = rowptr[d], end = rowptr[d+1];
    const float edv = ed[d];
    float acc = 0.f, wsum = 0.f;
    int k = beg;
    const int kend4 = beg + ((end - beg) & ~3);
    if (k < kend4) {
      int s0 = csrc[k], s1 = csrc[k+1], s2 = csrc[k+2], s3 = csrc[k+3];
      for (;;) {
        float e0 = es[s0], e1 = es[s1], e2 = es[s2], e3 = es[s3];
        float x0 = (float)h2h[(size_t)s0*64 + lane];
        float x1 = (float)h2h[(size_t)s1*64 + lane];
        float x2 = (float)h2h[(size_t)s2*64 + lane];
        float x3 = (float)h2h[(size_t)s3*64 + lane];
        k += 4;
        const bool more = (k < kend4);
        int t0 = 0, t1 = 0, t2 = 0, t3 = 0;
        if (more) { t0 = csrc[k]; t1 = csrc[k+1]; t2 = csrc[k+2]; t3 = csrc[k+3]; }
        float w0 = __expf(lrelu02(e0 + edv));
        float w1 = __expf(lrelu02(e1 + edv));
        float w2 = __expf(lrelu02(e2 + edv));
        float w3 = __expf(lrelu02(e3 + edv));
        wsum += (w0 + w1) + (w2 + w3);
        acc += w0*x0 + w1*x1 + w2*x2 + w3*x3;
        if (!more) break;
        s0 = t0; s1 = t1; s2 = t2; s3 = t3;
      }
    }
    for (; k < end; ++k) {
      int s = csrc[k];
      float w = __expf(lrelu02(es[s] + edv));
      wsum += w;
      acc += w * (float)h2h[(size_t)s*64 + lane];
    }
    float a = acc / (wsum + 1e-16f);
    float ss = a*a;
    #pragma unroll
    for (int o = 32; o; o >>= 1) ss += __shfl_xor(ss, o);
    float n  = fmaxf(sqrtf(ss), EPSF);
    float sc = tanhf(n) / n;                    // expmap0 scale
    out[(size_t)d*64 + lane] = a * sc;
  }
}

extern "C" void kernel_launch(void* const* d_in, const int* in_sizes, int n_in,
                              void* d_out, int out_size, void* d_ws, size_t ws_size,
                              hipStream_t stream) {
  const float* x      = (const float*)d_in[0];
  const float* W1     = (const float*)d_in[1];
  const float* a_src1 = (const float*)d_in[2];
  const float* a_dst1 = (const float*)d_in[3];
  const float* W2     = (const float*)d_in[4];
  const float* a_src2 = (const float*)d_in[5];
  const float* a_dst2 = (const float*)d_in[6];
  const int*   ei0    = (const int*)d_in[7];
  const int*   ei1    = (const int*)d_in[8];
  const int N  = in_sizes[0] / 128;
  const int E0 = in_sizes[7] / 2;
  const int E1 = in_sizes[8] / 2;
  const int* src0 = ei0;  const int* dst0 = ei0 + E0;
  const int* src1 = ei1;  const int* dst1 = ei1 + E1;
  float* out = (float*)d_out;
  const int nb = (N + 127) >> 7;

  float* ws = (float*)d_ws;
  size_t o = 0;
  float* es1   = ws + o; o += (size_t)N*4;
  float* ed1   = ws + o; o += (size_t)N*4;
  float* es2   = ws + o; o += (size_t)N;
  float* ed2   = ws + o; o += (size_t)N;
  float* w1a   = ws + o; o += 512;
  float* w1b   = ws + o; o += 512;
  _Float16* lxh = (_Float16*)(ws + o); o += (size_t)N*64;   // N*128 halves
  _Float16* w1t = (_Float16*)(ws + o); o += 16384;          // 32768 halves
  _Float16* w2t = (_Float16*)(ws + o); o += 8192;           // 16384 halves
  _Float16* h1h = (_Float16*)(ws + o); o += (size_t)N*128;  // N*256 halves
  _Float16* t2h = (_Float16*)(ws + o); o += (size_t)N*128;  // N*256 halves
  _Float16* h2h = (_Float16*)(ws + o); o += (size_t)N*32;   // N*64 halves
  o += (o & 1);                                             // 8B align
  half4* w0    = (half4*)(ws + o); o += (size_t)E0*2;       // E0*4 halves
  u64* temp0 = (u64*)(ws + o); o += (size_t)E0*2;
  u64* temp1 = (u64*)(ws + o); o += (size_t)E1*2;
  int* iws = (int*)(ws + o);
  size_t io = 0;
  int* rowptr0 = iws + io; io += N + 1;
  int* rowptr1 = iws + io; io += N + 1;
  int* bcnt0   = iws + io; io += NBMAX;  // bcnt0/bcnt1 adjacent: one memset
  int* bcnt1   = iws + io; io += NBMAX;
  int* bbase0  = iws + io; io += NBMAX + 1;
  int* bbase1  = iws + io; io += NBMAX + 1;
  int* bcur0   = iws + io; io += NBMAX;
  int* bcur1   = iws + io; io += NBMAX;
  int* csrc0   = iws + io; io += E0;
  int* csrc1   = iws + io; io += E1;

  dim3 blk(256);
  const int blocksA0 = (E0 + 4095) / 4096;
  const int blocksA1 = (E1 + 4095) / 4096;
  hipMemsetAsync(bcnt0, 0, 2*NBMAX*sizeof(int), stream);
  // precompute: w1a/w1b, W1^T/W2^T fp16, lx + es1/ed1 (bucketB2 consumes es1/ed1)
  k_w1ab   <<<1, 512, 0, stream>>>(W1, a_src1, a_dst1, w1a, w1b);
  k_w1prep <<<128, blk, 0, stream>>>(W1, w1t);
  k_w2prep <<<64, blk, 0, stream>>>(W2, w2t);
  k_lx_es  <<<2048, blk, 0, stream>>>(x, w1a, w1b, lxh, es1, ed1, N);
  // CSR build (+ graph-0 edge weights fused into bucketB2)
  k_bhist  <<<1024, blk, 0, stream>>>(dst0, E0, dst1, E1, bcnt0, bcnt1, nb);
  k_bscan  <<<1, 1024, 0, stream>>>(bcnt0, bbase0, bcur0, bcnt1, bbase1, bcur1, nb);
  k_bucketA<<<blocksA0 + blocksA1, blk, 0, stream>>>(
      src0, dst0, bcur0, temp0, E0, blocksA0, src1, dst1, bcur1, temp1, E1, nb);
  k_bucketB2<<<2*nb, blk, 0, stream>>>(temp0, bbase0, rowptr0, csrc0,
                                       es1, ed1, w0,
                                       temp1, bbase1, rowptr1, csrc1, N, nb);
  // layer-1 GEMM on matrix cores
  k_gemm1_mfma<<<(N+31)/32, blk, 0, stream>>>(lxh, w1t, h1h, N);
  // layer-1 aggregation (pipelined gather) + fused maps -> t2h
  k_agg1_csr<<<2048, blk, 0, stream>>>(rowptr0, csrc0, w0, h1h, t2h, N);
  // layer-2 GEMM on matrix cores (+ es2/ed2 epilogue)
  k_gemm2_mfma<<<(N+31)/32, blk, 0, stream>>>(t2h, w2t, a_src2, a_dst2,
                                              h2h, es2, ed2, N);
  k_agg2_csr<<<2048, blk, 0, stream>>>(rowptr1, csrc1, es2, ed2, h2h, out, N);
}

// Round 26
// 253.640 us; speedup vs baseline: 1.2748x; 1.1442x over previous
//
#include <hip/hip_runtime.h>

#define EPSF 1e-7f
#define NBMAX 512   // max dst-buckets (ceil(N/128)); N=50000 -> 391

typedef __attribute__((ext_vector_type(4))) _Float16 half4;
typedef __attribute__((ext_vector_type(8))) _Float16 half8;
typedef __attribute__((ext_vector_type(2))) _Float16 half2v;
typedef __attribute__((ext_vector_type(4))) float f32x4;
typedef unsigned long long u64;

__device__ __forceinline__ float lrelu02(float x){ return x > 0.f ? x : 0.2f*x; }

// ---------------- merged precompute: w1t, w2t, bcnt zero, lx = logmap0(x) ----------------
__global__ __launch_bounds__(256) void k_pre(
    const float* __restrict__ W1, const float* __restrict__ W2,
    const float* __restrict__ x,
    _Float16* __restrict__ w1t, _Float16* __restrict__ w2t,
    int* __restrict__ bcnt, _Float16* __restrict__ lxh, int N) {
  const int b = blockIdx.x, tid = threadIdx.x;
  if (b < 128) {                       // w1t [256][128] = W1^T fp16
    int idx = b*256 + tid;
    int j = idx >> 7, k = idx & 127;
    w1t[idx] = (_Float16)W1[(size_t)k*256 + j];
    return;
  }
  if (b < 192) {                       // w2t [64][256] = W2^T fp16
    int idx = (b-128)*256 + tid;
    int j = idx >> 8, k = idx & 255;
    w2t[idx] = (_Float16)W2[(size_t)k*64 + j];
    return;
  }
  if (b == 192) {                      // zero bucket counters (2*NBMAX ints)
    for (int i = tid; i < 2*NBMAX; i += 256) bcnt[i] = 0;
    return;
  }
  // lx = logmap0(x) fp16: wave per row
  int tidg = (b - 193)*256 + tid;
  int wid = tidg >> 6, lane = tidg & 63;
  int nw = (gridDim.x - 193) * 4;
  for (int row = wid; row < N; row += nw) {
    float2 v = *(const float2*)(x + (size_t)row*128 + lane*2);
    float ss = v.x*v.x + v.y*v.y;
    #pragma unroll
    for (int o = 32; o; o >>= 1) ss += __shfl_xor(ss, o);
    float n  = fmaxf(sqrtf(ss), EPSF);
    float nc = fminf(n, 1.f - 1e-5f);
    float sc = atanhf(nc) / n;                 // logmap0 scale
    half2v hv; hv.x = (_Float16)(v.x*sc); hv.y = (_Float16)(v.y*sc);
    *(half2v*)(lxh + (size_t)row*128 + lane*2) = hv;
  }
}

// ---------------- CSR build (bucket-local, no N-sized scan) ----------------
__global__ __launch_bounds__(256) void k_bhist(
    const int* __restrict__ dst0, int E0, const int* __restrict__ dst1, int E1,
    int* __restrict__ bcnt0, int* __restrict__ bcnt1, int nb) {
  __shared__ int h0[NBMAX], h1[NBMAX];
  const int tid = threadIdx.x;
  const int g = blockIdx.x*blockDim.x + tid;
  const int stride = gridDim.x*blockDim.x;
  for (int i = tid; i < nb; i += 256) { h0[i] = 0; h1[i] = 0; }
  __syncthreads();
  for (int i = g; i < E0; i += stride) atomicAdd(&h0[dst0[i] >> 7], 1);
  for (int i = g; i < E1; i += stride) atomicAdd(&h1[dst1[i] >> 7], 1);
  __syncthreads();
  for (int i = tid; i < nb; i += 256) {
    if (h0[i]) atomicAdd(&bcnt0[i], h0[i]);
    if (h1[i]) atomicAdd(&bcnt1[i], h1[i]);
  }
}

__global__ __launch_bounds__(1024) void k_bscan(
    const int* __restrict__ bcnt0, int* __restrict__ bbase0, int* __restrict__ bcur0,
    const int* __restrict__ bcnt1, int* __restrict__ bbase1, int* __restrict__ bcur1,
    int nb) {
  __shared__ int wt[16];
  const int tid = threadIdx.x;
  const int half = tid >> 9, idx = tid & 511;
  const int* bcnt = half ? bcnt1 : bcnt0;
  int* bbase = half ? bbase1 : bbase0;
  int* bcur  = half ? bcur1  : bcur0;
  int v = (idx < nb) ? bcnt[idx] : 0;
  const int lane = tid & 63, w = tid >> 6;
  int inc = v;
  #pragma unroll
  for (int o = 1; o < 64; o <<= 1) { int t = __shfl_up(inc, o); if (lane >= o) inc += t; }
  if (lane == 63) wt[w] = inc;
  __syncthreads();
  int woff = 0;
  for (int i = half*8; i < w; ++i) woff += wt[i];
  int excl = woff + inc - v;
  if (idx < nb) { bbase[idx] = excl; bcur[idx] = excl; }
  if (idx == nb-1) bbase[nb] = excl + v;
}

__global__ __launch_bounds__(256) void k_bucketA(
    const int* __restrict__ src0, const int* __restrict__ dst0,
    int* __restrict__ bcur0, u64* __restrict__ temp0, int E0, int blocksA0,
    const int* __restrict__ src1, const int* __restrict__ dst1,
    int* __restrict__ bcur1, u64* __restrict__ temp1, int E1, int nb) {
  const int g0 = (blockIdx.x < blocksA0);
  const int* src = g0 ? src0 : src1;
  const int* dst = g0 ? dst0 : dst1;
  int* bcur      = g0 ? bcur0 : bcur1;
  u64* temp      = g0 ? temp0 : temp1;
  const int E    = g0 ? E0 : E1;
  const int cb   = g0 ? blockIdx.x : blockIdx.x - blocksA0;
  __shared__ int hist[NBMAX];
  __shared__ int lbase[NBMAX];
  const int tid = threadIdx.x;
  const int chunk0 = cb * 4096;
  const int e_end = min(chunk0 + 4096, E);
  for (int i = tid; i < nb; i += 256) hist[i] = 0;
  __syncthreads();
  for (int i = chunk0 + tid; i < e_end; i += 256)
    atomicAdd(&hist[dst[i] >> 7], 1);
  __syncthreads();
  for (int bn = tid; bn < nb; bn += 256) {
    int c = hist[bn];
    lbase[bn] = c ? atomicAdd(&bcur[bn], c) : 0;
    hist[bn] = 0;
  }
  __syncthreads();
  for (int i = chunk0 + tid; i < e_end; i += 256) {
    int d = dst[i];
    int bn = d >> 7;
    int off = atomicAdd(&hist[bn], 1);
    temp[(size_t)lbase[bn] + off] = ((u64)(unsigned)d << 32) | (unsigned)src[i];
  }
}

// pass B: per bucket, per-dst count + local scan -> rowptr; scatter csrc.
// For graph 0 additionally: per-edge attention weights (fp16).
__global__ __launch_bounds__(256) void k_bucketB2(
    const u64* __restrict__ temp0, const int* __restrict__ bbase0,
    int* __restrict__ rowptr0, int* __restrict__ csrc0,
    const float* __restrict__ es1, const float* __restrict__ ed1,
    half4* __restrict__ w0,
    const u64* __restrict__ temp1, const int* __restrict__ bbase1,
    int* __restrict__ rowptr1, int* __restrict__ csrc1, int N, int nb) {
  const int g0 = (blockIdx.x < nb);
  const u64* temp = g0 ? temp0 : temp1;
  const int* bbase = g0 ? bbase0 : bbase1;
  int* rowptr = g0 ? rowptr0 : rowptr1;
  int* csrc   = g0 ? csrc0 : csrc1;
  const int b = g0 ? blockIdx.x : blockIdx.x - nb;
  __shared__ int lcnt[128];
  __shared__ int lcur[128];
  __shared__ int wt4[4];
  __shared__ float ledv[512];
  const int tid = threadIdx.x;
  const int d0 = b << 7;
  const int d1 = min(d0 + 128, N);
  const int lo = bbase[b], hi = bbase[b+1];
  if (tid < 128) lcnt[tid] = 0;
  if (g0) {
    for (int i = tid; i < (d1 - d0)*4; i += 256) ledv[i] = ed1[d0*4 + i];
  }
  __syncthreads();
  for (int k = lo + tid; k < hi; k += 256)
    atomicAdd(&lcnt[(int)(temp[k] >> 32) - d0], 1);
  __syncthreads();
  int v = (tid < 128) ? lcnt[tid] : 0;
  const int lane = tid & 63, w = tid >> 6;
  int inc = v;
  #pragma unroll
  for (int o = 1; o < 64; o <<= 1) { int t = __shfl_up(inc, o); if (lane >= o) inc += t; }
  if (lane == 63) wt4[w] = inc;
  __syncthreads();
  int woff = 0;
  for (int i = 0; i < w; ++i) woff += wt4[i];
  int excl = lo + woff + inc - v;
  if (tid < d1 - d0) { rowptr[d0 + tid] = excl; lcur[tid] = excl; }
  if (b == nb-1 && tid == 0) rowptr[N] = hi;
  __syncthreads();
  for (int k = lo + tid; k < hi; k += 256) {
    u64 p = temp[k];
    int d = (int)(p >> 32);
    int s = (int)(unsigned)p;
    int pos = atomicAdd(&lcur[d - d0], 1);
    csrc[pos] = s;
    if (g0) {
      float4 e = *(const float4*)(es1 + (size_t)s*4);
      int ld = (d - d0)*4;
      half4 wh;
      wh.x = (_Float16)__expf(lrelu02(e.x + ledv[ld+0]));
      wh.y = (_Float16)__expf(lrelu02(e.y + ledv[ld+1]));
      wh.z = (_Float16)__expf(lrelu02(e.z + ledv[ld+2]));
      wh.w = (_Float16)__expf(lrelu02(e.w + ledv[ld+3]));
      w0[pos] = wh;
    }
  }
}

// ------------- gemm1 via MFMA: h1 = lx @ W1 (fp16 in, f32 acc, fp16 out)
//   + epilogue: es1/ed1 [N,4] from the h1 LDS tile
#define LXP 136   // padded halves per lx row in LDS
#define H1P 264   // padded halves per h1 row in LDS
__global__ __launch_bounds__(256) void k_gemm1_mfma(
    const _Float16* __restrict__ lxh, const _Float16* __restrict__ w1t,
    const float* __restrict__ a_src, const float* __restrict__ a_dst,
    _Float16* __restrict__ h1h, float* __restrict__ es, float* __restrict__ ed, int N) {
  __shared__ _Float16 lxs[32*LXP];   // ~8.5 KB
  __shared__ _Float16 h1s[32*H1P];   // ~16.5 KB
  const int tid = threadIdx.x;
  const int block0 = blockIdx.x * 32;
  const int vrows = min(32, N - block0);
  for (int i = tid; i < 512; i += 256) {
    int r = i >> 4, c = (i & 15) * 8;
    uint4 v = make_uint4(0u,0u,0u,0u);
    if (r < vrows) v = *(const uint4*)(lxh + (size_t)(block0 + r)*128 + c);
    *(uint4*)(lxs + r*LXP + c) = v;
  }
  __syncthreads();
  const int wv = tid >> 6, lane = tid & 63;
  const int rt = wv & 1;               // row-tile (16 rows)
  const int ch = wv >> 1;              // col-half (128 cols)
  const int arow = rt*16 + (lane & 15);
  const int koff = (lane >> 4) * 8;
  f32x4 acc[8];
  #pragma unroll
  for (int t = 0; t < 8; ++t) acc[t] = (f32x4){0.f,0.f,0.f,0.f};
  #pragma unroll
  for (int ks = 0; ks < 4; ++ks) {
    half8 a = *(const half8*)(lxs + arow*LXP + ks*32 + koff);
    #pragma unroll
    for (int t = 0; t < 8; ++t) {
      const int col0 = ch*128 + t*16;
      half8 b = *(const half8*)(w1t + (size_t)(col0 + (lane & 15))*128 + ks*32 + koff);
      acc[t] = __builtin_amdgcn_mfma_f32_16x16x32_f16(a, b, acc[t], 0, 0, 0);
    }
  }
  #pragma unroll
  for (int t = 0; t < 8; ++t) {
    const int col = ch*128 + t*16 + (lane & 15);
    #pragma unroll
    for (int r = 0; r < 4; ++r) {
      const int row = rt*16 + (lane >> 4)*4 + r;
      h1s[row*H1P + col] = (_Float16)acc[t][r];
    }
  }
  __syncthreads();
  for (int i = tid; i < 1024; i += 256) {
    int r = i >> 5, c = (i & 31) * 8;
    if (r < vrows) {
      uint4 v = *(const uint4*)(h1s + r*H1P + c);
      *(uint4*)(h1h + (size_t)(block0 + r)*256 + c) = v;
    }
  }
  // epilogue: es/ed per (row, head) from h1s; lane owns cols lane*4..+3
  const int head = lane >> 4;
  const float4 as4 = *(const float4*)(a_src + lane*4);
  const float4 ad4 = *(const float4*)(a_dst + lane*4);
  #pragma unroll
  for (int r8 = 0; r8 < 8; ++r8) {
    int rl = wv*8 + r8;
    int row = block0 + rl;
    if (row >= N) break;
    half4 hv = *(const half4*)(h1s + rl*H1P + lane*4);
    float ax = (float)hv.x, ay = (float)hv.y, az = (float)hv.z, aw = (float)hv.w;
    float ps = ax*as4.x + ay*as4.y + az*as4.z + aw*as4.w;
    float pd = ax*ad4.x + ay*ad4.y + az*ad4.z + aw*ad4.w;
    #pragma unroll
    for (int o = 8; o; o >>= 1) { ps += __shfl_xor(ps, o); pd += __shfl_xor(pd, o); }
    if ((lane & 15) == 0) { es[row*4 + head] = ps; ed[row*4 + head] = pd; }
  }
}

// ------------- layer1 aggregation: pipelined gather + packed fdot2 accumulation -----------
__global__ void k_agg1_csr(const int* __restrict__ rowptr, const int* __restrict__ csrc,
                           const half4* __restrict__ w0,
                           const _Float16* __restrict__ h1h, _Float16* __restrict__ t2h,
                           int N) {
  int tidg = blockIdx.x*blockDim.x + threadIdx.x;
  int wid = tidg >> 6, lane = tidg & 63;
  int nw = (gridDim.x * blockDim.x) >> 6;
  const int h = lane >> 4;
  const _Float16* wp = (const _Float16*)w0;
  half2v ones; ones.x = (_Float16)1.f; ones.y = (_Float16)1.f;
  for (int d = wid; d < N; d += nw) {
    const int beg = rowptr[d], end = rowptr[d+1];
    float4 acc = make_float4(0.f,0.f,0.f,0.f);
    float wsum = 0.f;
    int k = beg;
    const int kend4 = beg + ((end - beg) & ~3);
    if (k < kend4) {
      int s0 = csrc[k], s1 = csrc[k+1], s2 = csrc[k+2], s3 = csrc[k+3];
      half2v wab, wcd;
      wab.x = wp[(size_t)(k+0)*4 + h]; wab.y = wp[(size_t)(k+1)*4 + h];
      wcd.x = wp[(size_t)(k+2)*4 + h]; wcd.y = wp[(size_t)(k+3)*4 + h];
      for (;;) {
        half4 v0 = *(const half4*)(h1h + (size_t)s0*256 + lane*4);
        half4 v1 = *(const half4*)(h1h + (size_t)s1*256 + lane*4);
        half4 v2 = *(const half4*)(h1h + (size_t)s2*256 + lane*4);
        half4 v3 = *(const half4*)(h1h + (size_t)s3*256 + lane*4);
        k += 4;
        const bool more = (k < kend4);
        int t0 = 0, t1 = 0, t2 = 0, t3 = 0;
        half2v uab, ucd;
        uab.x = uab.y = ucd.x = ucd.y = (_Float16)0.f;
        if (more) {
          t0 = csrc[k]; t1 = csrc[k+1]; t2 = csrc[k+2]; t3 = csrc[k+3];
          uab.x = wp[(size_t)(k+0)*4 + h]; uab.y = wp[(size_t)(k+1)*4 + h];
          ucd.x = wp[(size_t)(k+2)*4 + h]; ucd.y = wp[(size_t)(k+3)*4 + h];
        }
        wsum = __builtin_amdgcn_fdot2(wab, ones, wsum, false);
        wsum = __builtin_amdgcn_fdot2(wcd, ones, wsum, false);
        half2v p;
        p.x = v0.x; p.y = v1.x;
        acc.x = __builtin_amdgcn_fdot2(p, wab, acc.x, false);
        p.x = v2.x; p.y = v3.x;
        acc.x = __builtin_amdgcn_fdot2(p, wcd, acc.x, false);
        p.x = v0.y; p.y = v1.y;
        acc.y = __builtin_amdgcn_fdot2(p, wab, acc.y, false);
        p.x = v2.y; p.y = v3.y;
        acc.y = __builtin_amdgcn_fdot2(p, wcd, acc.y, false);
        p.x = v0.z; p.y = v1.z;
        acc.z = __builtin_amdgcn_fdot2(p, wab, acc.z, false);
        p.x = v2.z; p.y = v3.z;
        acc.z = __builtin_amdgcn_fdot2(p, wcd, acc.z, false);
        p.x = v0.w; p.y = v1.w;
        acc.w = __builtin_amdgcn_fdot2(p, wab, acc.w, false);
        p.x = v2.w; p.y = v3.w;
        acc.w = __builtin_amdgcn_fdot2(p, wcd, acc.w, false);
        if (!more) break;
        s0 = t0; s1 = t1; s2 = t2; s3 = t3;
        wab = uab; wcd = ucd;
      }
    }
    for (; k < end; ++k) {
      int s = csrc[k];
      float wa = (float)wp[(size_t)k*4 + h];
      half4 hv = *(const half4*)(h1h + (size_t)s*256 + lane*4);
      wsum += wa;
      acc.x += wa*(float)hv.x; acc.y += wa*(float)hv.y;
      acc.z += wa*(float)hv.z; acc.w += wa*(float)hv.w;
    }
    float inv = 1.f / (wsum + 1e-16f);
    float ax = acc.x*inv, ay = acc.y*inv, az = acc.z*inv, aw = acc.w*inv;
    float ss = ax*ax + ay*ay + az*az + aw*aw;
    #pragma unroll
    for (int o = 32; o; o >>= 1) ss += __shfl_xor(ss, o);
    float n  = fmaxf(sqrtf(ss), EPSF);
    float s1 = tanhf(n) / n;                    // expmap0 scale
    float n2 = fmaxf(s1 * n, EPSF);             // = tanh(n), clamped
    float nc = fminf(n2, 1.f - 1e-5f);
    float sc = s1 * atanhf(nc) / n2;
    half4 o4; o4.x = (_Float16)(ax*sc); o4.y = (_Float16)(ay*sc);
              o4.z = (_Float16)(az*sc); o4.w = (_Float16)(aw*sc);
    *(half4*)(t2h + (size_t)d*256 + lane*4) = o4;
  }
}

// ------------- gemm2 via MFMA: h2 = t2 @ W2 (fp16 in, f32 acc); es2/ed2 epilogue
#define T2SP 264  // padded halves per t2 row in LDS
#define H2SP 72   // padded halves per h2 row in LDS
__global__ __launch_bounds__(256) void k_gemm2_mfma(
    const _Float16* __restrict__ t2h, const _Float16* __restrict__ w2t,
    const float* __restrict__ a_src, const float* __restrict__ a_dst,
    _Float16* __restrict__ h2h, float* __restrict__ es, float* __restrict__ ed, int N) {
  __shared__ _Float16 t2s[32*T2SP];  // ~16.9 KB
  __shared__ _Float16 h2s[32*H2SP];  // ~4.6 KB
  const int tid = threadIdx.x;
  const int block0 = blockIdx.x * 32;
  const int vrows = min(32, N - block0);
  for (int i = tid; i < 1024; i += 256) {
    int r = i >> 5, c = (i & 31) * 8;
    uint4 v = make_uint4(0u,0u,0u,0u);
    if (r < vrows) v = *(const uint4*)(t2h + (size_t)(block0 + r)*256 + c);
    *(uint4*)(t2s + r*T2SP + c) = v;
  }
  __syncthreads();
  const int wv = tid >> 6, lane = tid & 63;
  const int rt = wv & 1;
  const int ch = wv >> 1;
  const int arow = rt*16 + (lane & 15);
  const int koff = (lane >> 4) * 8;
  f32x4 acc[2];
  acc[0] = (f32x4){0.f,0.f,0.f,0.f};
  acc[1] = (f32x4){0.f,0.f,0.f,0.f};
  #pragma unroll
  for (int ks = 0; ks < 8; ++ks) {
    half8 a = *(const half8*)(t2s + arow*T2SP + ks*32 + koff);
    #pragma unroll
    for (int t = 0; t < 2; ++t) {
      const int col0 = ch*32 + t*16;
      half8 b = *(const half8*)(w2t + (size_t)(col0 + (lane & 15))*256 + ks*32 + koff);
      acc[t] = __builtin_amdgcn_mfma_f32_16x16x32_f16(a, b, acc[t], 0, 0, 0);
    }
  }
  #pragma unroll
  for (int t = 0; t < 2; ++t) {
    const int col = ch*32 + t*16 + (lane & 15);
    #pragma unroll
    for (int r = 0; r < 4; ++r) {
      const int row = rt*16 + (lane >> 4)*4 + r;
      h2s[row*H2SP + col] = (_Float16)acc[t][r];
    }
  }
  __syncthreads();
  {
    int i = tid;
    int r = i >> 3, c = (i & 7) * 8;
    if (r < vrows) {
      uint4 v = *(const uint4*)(h2s + r*H2SP + c);
      *(uint4*)(h2h + (size_t)(block0 + r)*64 + c) = v;
    }
  }
  const int jj = (lane & 15) * 4;
  const int rg = lane >> 4;
  const int rbase = wv*8 + rg*2;
  const float4 as4 = *(const float4*)(a_src + jj);
  const float4 ad4 = *(const float4*)(a_dst + jj);
  #pragma unroll
  for (int rr = 0; rr < 2; ++rr) {
    int row = block0 + rbase + rr;
    if (row < N) {
      half4 hv = *(const half4*)(h2s + (rbase + rr)*H2SP + jj);
      float ax = (float)hv.x, ay = (float)hv.y, az = (float)hv.z, aw = (float)hv.w;
      float ps = ax*as4.x + ay*as4.y + az*as4.z + aw*as4.w;
      float pd = ax*ad4.x + ay*ad4.y + az*ad4.z + aw*ad4.w;
      #pragma unroll
      for (int o = 8; o; o >>= 1) { ps += __shfl_xor(ps, o); pd += __shfl_xor(pd, o); }
      if ((lane & 15) == 0) { es[row] = ps; ed[row] = pd; }
    }
  }
}

// ------------- layer2 aggregation (CSR, wave per dst, pipelined) + fused expmap0 ---------
__global__ void k_agg2_csr(const int* __restrict__ rowptr, const int* __restrict__ csrc,
                           const float* __restrict__ es, const float* __restrict__ ed,
                           const _Float16* __restrict__ h2h, float* __restrict__ out, int N) {
  int tidg = blockIdx.x*blockDim.x + threadIdx.x;
  int wid = tidg >> 6, lane = tidg & 63;
  int nw = (gridDim.x * blockDim.x) >> 6;
  for (int d = wid; d < N; d += nw) {
    const int beg = rowptr[d], end = rowptr[d+1];
    const float edv = ed[d];
    float acc = 0.f, wsum = 0.f;
    int k = beg;
    const int kend4 = beg + ((end - beg) & ~3);
    if (k < kend4) {
      int s0 = csrc[k], s1 = csrc[k+1], s2 = csrc[k+2], s3 = csrc[k+3];
      for (;;) {
        float e0 = es[s0], e1 = es[s1], e2 = es[s2], e3 = es[s3];
        float x0 = (float)h2h[(size_t)s0*64 + lane];
        float x1 = (float)h2h[(size_t)s1*64 + lane];
        float x2 = (float)h2h[(size_t)s2*64 + lane];
        float x3 = (float)h2h[(size_t)s3*64 + lane];
        k += 4;
        const bool more = (k < kend4);
        int t0 = 0, t1 = 0, t2 = 0, t3 = 0;
        if (more) { t0 = csrc[k]; t1 = csrc[k+1]; t2 = csrc[k+2]; t3 = csrc[k+3]; }
        float w0 = __expf(lrelu02(e0 + edv));
        float w1 = __expf(lrelu02(e1 + edv));
        float w2 = __expf(lrelu02(e2 + edv));
        float w3 = __expf(lrelu02(e3 + edv));
        wsum += (w0 + w1) + (w2 + w3);
        acc += w0*x0 + w1*x1 + w2*x2 + w3*x3;
        if (!more) break;
        s0 = t0; s1 = t1; s2 = t2; s3 = t3;
      }
    }
    for (; k < end; ++k) {
      int s = csrc[k];
      float w = __expf(lrelu02(es[s] + edv));
      wsum += w;
      acc += w * (float)h2h[(size_t)s*64 + lane];
    }
    float a = acc / (wsum + 1e-16f);
    float ss = a*a;
    #pragma unroll
    for (int o = 32; o; o >>= 1) ss += __shfl_xor(ss, o);
    float n  = fmaxf(sqrtf(ss), EPSF);
    float sc = tanhf(n) / n;                    // expmap0 scale
    out[(size_t)d*64 + lane] = a * sc;
  }
}

extern "C" void kernel_launch(void* const* d_in, const int* in_sizes, int n_in,
                              void* d_out, int out_size, void* d_ws, size_t ws_size,
                              hipStream_t stream) {
  const float* x      = (const float*)d_in[0];
  const float* W1     = (const float*)d_in[1];
  const float* a_src1 = (const float*)d_in[2];
  const float* a_dst1 = (const float*)d_in[3];
  const float* W2     = (const float*)d_in[4];
  const float* a_src2 = (const float*)d_in[5];
  const float* a_dst2 = (const float*)d_in[6];
  const int*   ei0    = (const int*)d_in[7];
  const int*   ei1    = (const int*)d_in[8];
  const int N  = in_sizes[0] / 128;
  const int E0 = in_sizes[7] / 2;
  const int E1 = in_sizes[8] / 2;
  const int* src0 = ei0;  const int* dst0 = ei0 + E0;
  const int* src1 = ei1;  const int* dst1 = ei1 + E1;
  float* out = (float*)d_out;
  const int nb = (N + 127) >> 7;

  float* ws = (float*)d_ws;
  size_t o = 0;
  float* es1   = ws + o; o += (size_t)N*4;
  float* ed1   = ws + o; o += (size_t)N*4;
  float* es2   = ws + o; o += (size_t)N;
  float* ed2   = ws + o; o += (size_t)N;
  _Float16* lxh = (_Float16*)(ws + o); o += (size_t)N*64;   // N*128 halves
  _Float16* w1t = (_Float16*)(ws + o); o += 16384;          // 32768 halves
  _Float16* w2t = (_Float16*)(ws + o); o += 8192;           // 16384 halves
  _Float16* h1h = (_Float16*)(ws + o); o += (size_t)N*128;  // N*256 halves
  _Float16* t2h = (_Float16*)(ws + o); o += (size_t)N*128;  // N*256 halves
  _Float16* h2h = (_Float16*)(ws + o); o += (size_t)N*32;   // N*64 halves
  o += (o & 1);                                             // 8B align
  half4* w0    = (half4*)(ws + o); o += (size_t)E0*2;       // E0*4 halves
  u64* temp0 = (u64*)(ws + o); o += (size_t)E0*2;
  u64* temp1 = (u64*)(ws + o); o += (size_t)E1*2;
  int* iws = (int*)(ws + o);
  size_t io = 0;
  int* rowptr0 = iws + io; io += N + 1;
  int* rowptr1 = iws + io; io += N + 1;
  int* bcnt0   = iws + io; io += NBMAX;  // bcnt0/bcnt1 adjacent: zeroed by k_pre
  int* bcnt1   = iws + io; io += NBMAX;
  int* bbase0  = iws + io; io += NBMAX + 1;
  int* bbase1  = iws + io; io += NBMAX + 1;
  int* bcur0   = iws + io; io += NBMAX;
  int* bcur1   = iws + io; io += NBMAX;
  int* csrc0   = iws + io; io += E0;
  int* csrc1   = iws + io; io += E1;

  dim3 blk(256);
  const int blocksA0 = (E0 + 4095) / 4096;
  const int blocksA1 = (E1 + 4095) / 4096;
  // merged precompute: w1t, w2t, bcnt zero, lx
  k_pre    <<<193 + 2048, blk, 0, stream>>>(W1, W2, x, w1t, w2t, bcnt0, lxh, N);
  // layer-1 GEMM on matrix cores (+ es1/ed1 epilogue; bucketB2 consumes them)
  k_gemm1_mfma<<<(N+31)/32, blk, 0, stream>>>(lxh, w1t, a_src1, a_dst1,
                                              h1h, es1, ed1, N);
  // CSR build (+ graph-0 edge weights fused into bucketB2)
  k_bhist  <<<1024, blk, 0, stream>>>(dst0, E0, dst1, E1, bcnt0, bcnt1, nb);
  k_bscan  <<<1, 1024, 0, stream>>>(bcnt0, bbase0, bcur0, bcnt1, bbase1, bcur1, nb);
  k_bucketA<<<blocksA0 + blocksA1, blk, 0, stream>>>(
      src0, dst0, bcur0, temp0, E0, blocksA0, src1, dst1, bcur1, temp1, E1, nb);
  k_bucketB2<<<2*nb, blk, 0, stream>>>(temp0, bbase0, rowptr0, csrc0,
                                       es1, ed1, w0,
                                       temp1, bbase1, rowptr1, csrc1, N, nb);
  // layer-1 aggregation (pipelined gather, fdot2) + fused maps -> t2h
  k_agg1_csr<<<2048, blk, 0, stream>>>(rowptr0, csrc0, w0, h1h, t2h, N);
  // layer-2 GEMM on matrix cores (+ es2/ed2 epilogue)
  k_gemm2_mfma<<<(N+31)/32, blk, 0, stream>>>(t2h, w2t, a_src2, a_dst2,
                                              h2h, es2, ed2, N);
  k_agg2_csr<<<2048, blk, 0, stream>>>(rowptr1, csrc1, es2, ed2, h2h, out, N);
}

// Round 27
// 229.057 us; speedup vs baseline: 1.4116x; 1.1073x over previous
//
#include <hip/hip_runtime.h>

#define EPSF 1e-7f
#define NBMAX 512   // max dst-buckets (ceil(N/128)); N=50000 -> 391

typedef __attribute__((ext_vector_type(4))) _Float16 half4;
typedef __attribute__((ext_vector_type(8))) _Float16 half8;
typedef __attribute__((ext_vector_type(2))) _Float16 half2v;
typedef __attribute__((ext_vector_type(4))) float f32x4;
typedef unsigned long long u64;

__device__ __forceinline__ float lrelu02(float x){ return x > 0.f ? x : 0.2f*x; }

// ------- merged precompute: w1t, w2t, partial dst-histograms, lx = logmap0(x) -------
//   blocks 0..127: w1t | 128..191: w2t | 192..703: 2x256 partial hists | 704+: lx
__global__ __launch_bounds__(256) void k_pre(
    const float* __restrict__ W1, const float* __restrict__ W2,
    const float* __restrict__ x,
    const int* __restrict__ dst0, int E0, const int* __restrict__ dst1, int E1,
    _Float16* __restrict__ w1t, _Float16* __restrict__ w2t,
    int* __restrict__ part0, int* __restrict__ part1,
    _Float16* __restrict__ lxh, int N) {
  const int b = blockIdx.x, tid = threadIdx.x;
  if (b < 128) {                       // w1t [256][128] = W1^T fp16
    int idx = b*256 + tid;
    int j = idx >> 7, k = idx & 127;
    w1t[idx] = (_Float16)W1[(size_t)k*256 + j];
    return;
  }
  if (b < 192) {                       // w2t [64][256] = W2^T fp16
    int idx = (b-128)*256 + tid;
    int j = idx >> 8, k = idx & 255;
    w2t[idx] = (_Float16)W2[(size_t)k*64 + j];
    return;
  }
  if (b < 704) {                       // partial histograms (256 blocks per graph)
    const int pb = b - 192;
    const int g = pb >> 8, p = pb & 255;
    const int* dst = g ? dst1 : dst0;
    const int E = g ? E1 : E0;
    int* part = g ? part1 : part0;
    __shared__ int hist[NBMAX];
    for (int i = tid; i < NBMAX; i += 256) hist[i] = 0;
    __syncthreads();
    const int per = (E + 255) >> 8;
    const int lo = p * per, hi = min(lo + per, E);
    for (int i = lo + tid; i < hi; i += 256)
      atomicAdd(&hist[dst[i] >> 7], 1);
    __syncthreads();
    for (int i = tid; i < NBMAX; i += 256) part[p*NBMAX + i] = hist[i];
    return;
  }
  // lx = logmap0(x) fp16: wave per row
  int tidg = (b - 704)*256 + tid;
  int wid = tidg >> 6, lane = tidg & 63;
  int nw = (gridDim.x - 704) * 4;
  for (int row = wid; row < N; row += nw) {
    float2 v = *(const float2*)(x + (size_t)row*128 + lane*2);
    float ss = v.x*v.x + v.y*v.y;
    #pragma unroll
    for (int o = 32; o; o >>= 1) ss += __shfl_xor(ss, o);
    float n  = fmaxf(sqrtf(ss), EPSF);
    float nc = fminf(n, 1.f - 1e-5f);
    float sc = atanhf(nc) / n;                 // logmap0 scale
    half2v hv; hv.x = (_Float16)(v.x*sc); hv.y = (_Float16)(v.y*sc);
    *(half2v*)(lxh + (size_t)row*128 + lane*2) = hv;
  }
}

__global__ __launch_bounds__(256) void k_bucketA(
    const int* __restrict__ src0, const int* __restrict__ dst0,
    int* __restrict__ bcur0, u64* __restrict__ temp0, int E0, int blocksA0,
    const int* __restrict__ src1, const int* __restrict__ dst1,
    int* __restrict__ bcur1, u64* __restrict__ temp1, int E1, int nb) {
  const int g0 = (blockIdx.x < blocksA0);
  const int* src = g0 ? src0 : src1;
  const int* dst = g0 ? dst0 : dst1;
  int* bcur      = g0 ? bcur0 : bcur1;
  u64* temp      = g0 ? temp0 : temp1;
  const int E    = g0 ? E0 : E1;
  const int cb   = g0 ? blockIdx.x : blockIdx.x - blocksA0;
  __shared__ int hist[NBMAX];
  __shared__ int lbase[NBMAX];
  const int tid = threadIdx.x;
  const int chunk0 = cb * 4096;
  const int e_end = min(chunk0 + 4096, E);
  for (int i = tid; i < nb; i += 256) hist[i] = 0;
  __syncthreads();
  for (int i = chunk0 + tid; i < e_end; i += 256)
    atomicAdd(&hist[dst[i] >> 7], 1);
  __syncthreads();
  for (int bn = tid; bn < nb; bn += 256) {
    int c = hist[bn];
    lbase[bn] = c ? atomicAdd(&bcur[bn], c) : 0;
    hist[bn] = 0;
  }
  __syncthreads();
  for (int i = chunk0 + tid; i < e_end; i += 256) {
    int d = dst[i];
    int bn = d >> 7;
    int off = atomicAdd(&hist[bn], 1);
    temp[(size_t)lbase[bn] + off] = ((u64)(unsigned)d << 32) | (unsigned)src[i];
  }
}

// pass B: per bucket, per-dst count + local scan -> rowptr; scatter csrc.
// For graph 0 additionally: per-edge attention weights (fp16).
__global__ __launch_bounds__(256) void k_bucketB2(
    const u64* __restrict__ temp0, const int* __restrict__ bbase0,
    int* __restrict__ rowptr0, int* __restrict__ csrc0,
    const float* __restrict__ es1, const float* __restrict__ ed1,
    half4* __restrict__ w0,
    const u64* __restrict__ temp1, const int* __restrict__ bbase1,
    int* __restrict__ rowptr1, int* __restrict__ csrc1, int N, int nb) {
  const int g0 = (blockIdx.x < nb);
  const u64* temp = g0 ? temp0 : temp1;
  const int* bbase = g0 ? bbase0 : bbase1;
  int* rowptr = g0 ? rowptr0 : rowptr1;
  int* csrc   = g0 ? csrc0 : csrc1;
  const int b = g0 ? blockIdx.x : blockIdx.x - nb;
  __shared__ int lcnt[128];
  __shared__ int lcur[128];
  __shared__ int wt4[4];
  __shared__ float ledv[512];
  const int tid = threadIdx.x;
  const int d0 = b << 7;
  const int d1 = min(d0 + 128, N);
  const int lo = bbase[b], hi = bbase[b+1];
  if (tid < 128) lcnt[tid] = 0;
  if (g0) {
    for (int i = tid; i < (d1 - d0)*4; i += 256) ledv[i] = ed1[d0*4 + i];
  }
  __syncthreads();
  for (int k = lo + tid; k < hi; k += 256)
    atomicAdd(&lcnt[(int)(temp[k] >> 32) - d0], 1);
  __syncthreads();
  int v = (tid < 128) ? lcnt[tid] : 0;
  const int lane = tid & 63, w = tid >> 6;
  int inc = v;
  #pragma unroll
  for (int o = 1; o < 64; o <<= 1) { int t = __shfl_up(inc, o); if (lane >= o) inc += t; }
  if (lane == 63) wt4[w] = inc;
  __syncthreads();
  int woff = 0;
  for (int i = 0; i < w; ++i) woff += wt4[i];
  int excl = lo + woff + inc - v;
  if (tid < d1 - d0) { rowptr[d0 + tid] = excl; lcur[tid] = excl; }
  if (b == nb-1 && tid == 0) rowptr[N] = hi;
  __syncthreads();
  for (int k = lo + tid; k < hi; k += 256) {
    u64 p = temp[k];
    int d = (int)(p >> 32);
    int s = (int)(unsigned)p;
    int pos = atomicAdd(&lcur[d - d0], 1);
    csrc[pos] = s;
    if (g0) {
      float4 e = *(const float4*)(es1 + (size_t)s*4);
      int ld = (d - d0)*4;
      half4 wh;
      wh.x = (_Float16)__expf(lrelu02(e.x + ledv[ld+0]));
      wh.y = (_Float16)__expf(lrelu02(e.y + ledv[ld+1]));
      wh.z = (_Float16)__expf(lrelu02(e.z + ledv[ld+2]));
      wh.w = (_Float16)__expf(lrelu02(e.w + ledv[ld+3]));
      w0[pos] = wh;
    }
  }
}

// ------------- gemm1 via MFMA: h1 = lx @ W1 (fp16 in, f32 acc, fp16 out)
//   + epilogue: es1/ed1 [N,4] from the h1 LDS tile
//   + 2 appended blocks: bucket-count scan (sums k_pre partials) -> bbase/bcur
#define LXP 136   // padded halves per lx row in LDS
#define H1P 264   // padded halves per h1 row in LDS
__global__ __launch_bounds__(256) void k_gemm1_mfma(
    const _Float16* __restrict__ lxh, const _Float16* __restrict__ w1t,
    const float* __restrict__ a_src, const float* __restrict__ a_dst,
    _Float16* __restrict__ h1h, float* __restrict__ es, float* __restrict__ ed,
    const int* __restrict__ part0, const int* __restrict__ part1,
    int* __restrict__ bbase0, int* __restrict__ bcur0,
    int* __restrict__ bbase1, int* __restrict__ bcur1, int nb, int N) {
  __shared__ _Float16 lxs[32*LXP];   // ~8.5 KB
  __shared__ _Float16 h1s[32*H1P];   // ~16.5 KB
  __shared__ int swt[4];
  const int tid = threadIdx.x;
  const int nblk = (N + 31) >> 5;
  if ((int)blockIdx.x >= nblk) {
    // ---- bucket scan for graph g (replaces k_bscan) ----
    const int g = (int)blockIdx.x - nblk;
    const int* part = g ? part1 : part0;
    int* bbase = g ? bbase1 : bbase0;
    int* bcur  = g ? bcur1  : bcur0;
    const int i0 = tid*2, i1 = tid*2 + 1;
    int v0 = 0, v1 = 0;
    for (int p = 0; p < 256; ++p) {
      v0 += part[p*NBMAX + i0];
      v1 += part[p*NBMAX + i1];
    }
    int s = v0 + v1;
    const int lane = tid & 63, w = tid >> 6;
    int inc = s;
    #pragma unroll
    for (int o = 1; o < 64; o <<= 1) { int t = __shfl_up(inc, o); if (lane >= o) inc += t; }
    if (lane == 63) swt[w] = inc;
    __syncthreads();
    int woff = 0;
    for (int i = 0; i < w; ++i) woff += swt[i];
    int excl = woff + inc - s;
    if (i0 < nb) { bbase[i0] = excl; bcur[i0] = excl; }
    if (i1 < nb) { bbase[i1] = excl + v0; bcur[i1] = excl + v0; }
    if (tid == 255) bbase[nb] = excl + s;   // beyond-nb partials are zero
    return;
  }
  const int block0 = blockIdx.x * 32;
  const int vrows = min(32, N - block0);
  for (int i = tid; i < 512; i += 256) {
    int r = i >> 4, c = (i & 15) * 8;
    uint4 v = make_uint4(0u,0u,0u,0u);
    if (r < vrows) v = *(const uint4*)(lxh + (size_t)(block0 + r)*128 + c);
    *(uint4*)(lxs + r*LXP + c) = v;
  }
  __syncthreads();
  const int wv = tid >> 6, lane = tid & 63;
  const int rt = wv & 1;               // row-tile (16 rows)
  const int ch = wv >> 1;              // col-half (128 cols)
  const int arow = rt*16 + (lane & 15);
  const int koff = (lane >> 4) * 8;
  f32x4 acc[8];
  #pragma unroll
  for (int t = 0; t < 8; ++t) acc[t] = (f32x4){0.f,0.f,0.f,0.f};
  #pragma unroll
  for (int ks = 0; ks < 4; ++ks) {
    half8 a = *(const half8*)(lxs + arow*LXP + ks*32 + koff);
    #pragma unroll
    for (int t = 0; t < 8; ++t) {
      const int col0 = ch*128 + t*16;
      half8 b = *(const half8*)(w1t + (size_t)(col0 + (lane & 15))*128 + ks*32 + koff);
      acc[t] = __builtin_amdgcn_mfma_f32_16x16x32_f16(a, b, acc[t], 0, 0, 0);
    }
  }
  #pragma unroll
  for (int t = 0; t < 8; ++t) {
    const int col = ch*128 + t*16 + (lane & 15);
    #pragma unroll
    for (int r = 0; r < 4; ++r) {
      const int row = rt*16 + (lane >> 4)*4 + r;
      h1s[row*H1P + col] = (_Float16)acc[t][r];
    }
  }
  __syncthreads();
  for (int i = tid; i < 1024; i += 256) {
    int r = i >> 5, c = (i & 31) * 8;
    if (r < vrows) {
      uint4 v = *(const uint4*)(h1s + r*H1P + c);
      *(uint4*)(h1h + (size_t)(block0 + r)*256 + c) = v;
    }
  }
  // epilogue: es/ed per (row, head) from h1s; lane owns cols lane*4..+3
  const int head = lane >> 4;
  const float4 as4 = *(const float4*)(a_src + lane*4);
  const float4 ad4 = *(const float4*)(a_dst + lane*4);
  #pragma unroll
  for (int r8 = 0; r8 < 8; ++r8) {
    int rl = wv*8 + r8;
    int row = block0 + rl;
    if (row >= N) break;
    half4 hv = *(const half4*)(h1s + rl*H1P + lane*4);
    float ax = (float)hv.x, ay = (float)hv.y, az = (float)hv.z, aw = (float)hv.w;
    float ps = ax*as4.x + ay*as4.y + az*as4.z + aw*as4.w;
    float pd = ax*ad4.x + ay*ad4.y + az*ad4.z + aw*ad4.w;
    #pragma unroll
    for (int o = 8; o; o >>= 1) { ps += __shfl_xor(ps, o); pd += __shfl_xor(pd, o); }
    if ((lane & 15) == 0) { es[row*4 + head] = ps; ed[row*4 + head] = pd; }
  }
}

// ------------- layer1 aggregation: pipelined gather + packed fdot2 accumulation -----------
__global__ void k_agg1_csr(const int* __restrict__ rowptr, const int* __restrict__ csrc,
                           const half4* __restrict__ w0,
                           const _Float16* __restrict__ h1h, _Float16* __restrict__ t2h,
                           int N) {
  int tidg = blockIdx.x*blockDim.x + threadIdx.x;
  int wid = tidg >> 6, lane = tidg & 63;
  int nw = (gridDim.x * blockDim.x) >> 6;
  const int h = lane >> 4;
  const _Float16* wp = (const _Float16*)w0;
  half2v ones; ones.x = (_Float16)1.f; ones.y = (_Float16)1.f;
  for (int d = wid; d < N; d += nw) {
    const int beg = rowptr[d], end = rowptr[d+1];
    float4 acc = make_float4(0.f,0.f,0.f,0.f);
    float wsum = 0.f;
    int k = beg;
    const int kend4 = beg + ((end - beg) & ~3);
    if (k < kend4) {
      int s0 = csrc[k], s1 = csrc[k+1], s2 = csrc[k+2], s3 = csrc[k+3];
      half2v wab, wcd;
      wab.x = wp[(size_t)(k+0)*4 + h]; wab.y = wp[(size_t)(k+1)*4 + h];
      wcd.x = wp[(size_t)(k+2)*4 + h]; wcd.y = wp[(size_t)(k+3)*4 + h];
      for (;;) {
        half4 v0 = *(const half4*)(h1h + (size_t)s0*256 + lane*4);
        half4 v1 = *(const half4*)(h1h + (size_t)s1*256 + lane*4);
        half4 v2 = *(const half4*)(h1h + (size_t)s2*256 + lane*4);
        half4 v3 = *(const half4*)(h1h + (size_t)s3*256 + lane*4);
        k += 4;
        const bool more = (k < kend4);
        int t0 = 0, t1 = 0, t2 = 0, t3 = 0;
        half2v uab, ucd;
        uab.x = uab.y = ucd.x = ucd.y = (_Float16)0.f;
        if (more) {
          t0 = csrc[k]; t1 = csrc[k+1]; t2 = csrc[k+2]; t3 = csrc[k+3];
          uab.x = wp[(size_t)(k+0)*4 + h]; uab.y = wp[(size_t)(k+1)*4 + h];
          ucd.x = wp[(size_t)(k+2)*4 + h]; ucd.y = wp[(size_t)(k+3)*4 + h];
        }
        wsum = __builtin_amdgcn_fdot2(wab, ones, wsum, false);
        wsum = __builtin_amdgcn_fdot2(wcd, ones, wsum, false);
        half2v p;
        p.x = v0.x; p.y = v1.x;
        acc.x = __builtin_amdgcn_fdot2(p, wab, acc.x, false);
        p.x = v2.x; p.y = v3.x;
        acc.x = __builtin_amdgcn_fdot2(p, wcd, acc.x, false);
        p.x = v0.y; p.y = v1.y;
        acc.y = __builtin_amdgcn_fdot2(p, wab, acc.y, false);
        p.x = v2.y; p.y = v3.y;
        acc.y = __builtin_amdgcn_fdot2(p, wcd, acc.y, false);
        p.x = v0.z; p.y = v1.z;
        acc.z = __builtin_amdgcn_fdot2(p, wab, acc.z, false);
        p.x = v2.z; p.y = v3.z;
        acc.z = __builtin_amdgcn_fdot2(p, wcd, acc.z, false);
        p.x = v0.w; p.y = v1.w;
        acc.w = __builtin_amdgcn_fdot2(p, wab, acc.w, false);
        p.x = v2.w; p.y = v3.w;
        acc.w = __builtin_amdgcn_fdot2(p, wcd, acc.w, false);
        if (!more) break;
        s0 = t0; s1 = t1; s2 = t2; s3 = t3;
        wab = uab; wcd = ucd;
      }
    }
    for (; k < end; ++k) {
      int s = csrc[k];
      float wa = (float)wp[(size_t)k*4 + h];
      half4 hv = *(const half4*)(h1h + (size_t)s*256 + lane*4);
      wsum += wa;
      acc.x += wa*(float)hv.x; acc.y += wa*(float)hv.y;
      acc.z += wa*(float)hv.z; acc.w += wa*(float)hv.w;
    }
    float inv = 1.f / (wsum + 1e-16f);
    float ax = acc.x*inv, ay = acc.y*inv, az = acc.z*inv, aw = acc.w*inv;
    float ss = ax*ax + ay*ay + az*az + aw*aw;
    #pragma unroll
    for (int o = 32; o; o >>= 1) ss += __shfl_xor(ss, o);
    float n  = fmaxf(sqrtf(ss), EPSF);
    float s1 = tanhf(n) / n;                    // expmap0 scale
    float n2 = fmaxf(s1 * n, EPSF);             // = tanh(n), clamped
    float nc = fminf(n2, 1.f - 1e-5f);
    float sc = s1 * atanhf(nc) / n2;
    half4 o4; o4.x = (_Float16)(ax*sc); o4.y = (_Float16)(ay*sc);
              o4.z = (_Float16)(az*sc); o4.w = (_Float16)(aw*sc);
    *(half4*)(t2h + (size_t)d*256 + lane*4) = o4;
  }
}

// ------------- gemm2 via MFMA: h2 = t2 @ W2 (fp16 in, f32 acc); es2/ed2 epilogue
#define T2SP 264  // padded halves per t2 row in LDS
#define H2SP 72   // padded halves per h2 row in LDS
__global__ __launch_bounds__(256) void k_gemm2_mfma(
    const _Float16* __restrict__ t2h, const _Float16* __restrict__ w2t,
    const float* __restrict__ a_src, const float* __restrict__ a_dst,
    _Float16* __restrict__ h2h, float* __restrict__ es, float* __restrict__ ed, int N) {
  __shared__ _Float16 t2s[32*T2SP];  // ~16.9 KB
  __shared__ _Float16 h2s[32*H2SP];  // ~4.6 KB
  const int tid = threadIdx.x;
  const int block0 = blockIdx.x * 32;
  const int vrows = min(32, N - block0);
  for (int i = tid; i < 1024; i += 256) {
    int r = i >> 5, c = (i & 31) * 8;
    uint4 v = make_uint4(0u,0u,0u,0u);
    if (r < vrows) v = *(const uint4*)(t2h + (size_t)(block0 + r)*256 + c);
    *(uint4*)(t2s + r*T2SP + c) = v;
  }
  __syncthreads();
  const int wv = tid >> 6, lane = tid & 63;
  const int rt = wv & 1;
  const int ch = wv >> 1;
  const int arow = rt*16 + (lane & 15);
  const int koff = (lane >> 4) * 8;
  f32x4 acc[2];
  acc[0] = (f32x4){0.f,0.f,0.f,0.f};
  acc[1] = (f32x4){0.f,0.f,0.f,0.f};
  #pragma unroll
  for (int ks = 0; ks < 8; ++ks) {
    half8 a = *(const half8*)(t2s + arow*T2SP + ks*32 + koff);
    #pragma unroll
    for (int t = 0; t < 2; ++t) {
      const int col0 = ch*32 + t*16;
      half8 b = *(const half8*)(w2t + (size_t)(col0 + (lane & 15))*256 + ks*32 + koff);
      acc[t] = __builtin_amdgcn_mfma_f32_16x16x32_f16(a, b, acc[t], 0, 0, 0);
    }
  }
  #pragma unroll
  for (int t = 0; t < 2; ++t) {
    const int col = ch*32 + t*16 + (lane & 15);
    #pragma unroll
    for (int r = 0; r < 4; ++r) {
      const int row = rt*16 + (lane >> 4)*4 + r;
      h2s[row*H2SP + col] = (_Float16)acc[t][r];
    }
  }
  __syncthreads();
  {
    int i = tid;
    int r = i >> 3, c = (i & 7) * 8;
    if (r < vrows) {
      uint4 v = *(const uint4*)(h2s + r*H2SP + c);
      *(uint4*)(h2h + (size_t)(block0 + r)*64 + c) = v;
    }
  }
  const int jj = (lane & 15) * 4;
  const int rg = lane >> 4;
  const int rbase = wv*8 + rg*2;
  const float4 as4 = *(const float4*)(a_src + jj);
  const float4 ad4 = *(const float4*)(a_dst + jj);
  #pragma unroll
  for (int rr = 0; rr < 2; ++rr) {
    int row = block0 + rbase + rr;
    if (row < N) {
      half4 hv = *(const half4*)(h2s + (rbase + rr)*H2SP + jj);
      float ax = (float)hv.x, ay = (float)hv.y, az = (float)hv.z, aw = (float)hv.w;
      float ps = ax*as4.x + ay*as4.y + az*as4.z + aw*as4.w;
      float pd = ax*ad4.x + ay*ad4.y + az*ad4.z + aw*ad4.w;
      #pragma unroll
      for (int o = 8; o; o >>= 1) { ps += __shfl_xor(ps, o); pd += __shfl_xor(pd, o); }
      if ((lane & 15) == 0) { es[row] = ps; ed[row] = pd; }
    }
  }
}

// ------------- layer2 aggregation (CSR, wave per dst, pipelined) + fused expmap0 ---------
__global__ void k_agg2_csr(const int* __restrict__ rowptr, const int* __restrict__ csrc,
                           const float* __restrict__ es, const float* __restrict__ ed,
                           const _Float16* __restrict__ h2h, float* __restrict__ out, int N) {
  int tidg = blockIdx.x*blockDim.x + threadIdx.x;
  int wid = tidg >> 6, lane = tidg & 63;
  int nw = (gridDim.x * blockDim.x) >> 6;
  for (int d = wid; d < N; d += nw) {
    const int beg = rowptr[d], end = rowptr[d+1];
    const float edv = ed[d];
    float acc = 0.f, wsum = 0.f;
    int k = beg;
    const int kend4 = beg + ((end - beg) & ~3);
    if (k < kend4) {
      int s0 = csrc[k], s1 = csrc[k+1], s2 = csrc[k+2], s3 = csrc[k+3];
      for (;;) {
        float e0 = es[s0], e1 = es[s1], e2 = es[s2], e3 = es[s3];
        float x0 = (float)h2h[(size_t)s0*64 + lane];
        float x1 = (float)h2h[(size_t)s1*64 + lane];
        float x2 = (float)h2h[(size_t)s2*64 + lane];
        float x3 = (float)h2h[(size_t)s3*64 + lane];
        k += 4;
        const bool more = (k < kend4);
        int t0 = 0, t1 = 0, t2 = 0, t3 = 0;
        if (more) { t0 = csrc[k]; t1 = csrc[k+1]; t2 = csrc[k+2]; t3 = csrc[k+3]; }
        float w0 = __expf(lrelu02(e0 + edv));
        float w1 = __expf(lrelu02(e1 + edv));
        float w2 = __expf(lrelu02(e2 + edv));
        float w3 = __expf(lrelu02(e3 + edv));
        wsum += (w0 + w1) + (w2 + w3);
        acc += w0*x0 + w1*x1 + w2*x2 + w3*x3;
        if (!more) break;
        s0 = t0; s1 = t1; s2 = t2; s3 = t3;
      }
    }
    for (; k < end; ++k) {
      int s = csrc[k];
      float w = __expf(lrelu02(es[s] + edv));
      wsum += w;
      acc += w * (float)h2h[(size_t)s*64 + lane];
    }
    float a = acc / (wsum + 1e-16f);
    float ss = a*a;
    #pragma unroll
    for (int o = 32; o; o >>= 1) ss += __shfl_xor(ss, o);
    float n  = fmaxf(sqrtf(ss), EPSF);
    float sc = tanhf(n) / n;                    // expmap0 scale
    out[(size_t)d*64 + lane] = a * sc;
  }
}

extern "C" void kernel_launch(void* const* d_in, const int* in_sizes, int n_in,
                              void* d_out, int out_size, void* d_ws, size_t ws_size,
                              hipStream_t stream) {
  const float* x      = (const float*)d_in[0];
  const float* W1     = (const float*)d_in[1];
  const float* a_src1 = (const float*)d_in[2];
  const float* a_dst1 = (const float*)d_in[3];
  const float* W2     = (const float*)d_in[4];
  const float* a_src2 = (const float*)d_in[5];
  const float* a_dst2 = (const float*)d_in[6];
  const int*   ei0    = (const int*)d_in[7];
  const int*   ei1    = (const int*)d_in[8];
  const int N  = in_sizes[0] / 128;
  const int E0 = in_sizes[7] / 2;
  const int E1 = in_sizes[8] / 2;
  const int* src0 = ei0;  const int* dst0 = ei0 + E0;
  const int* src1 = ei1;  const int* dst1 = ei1 + E1;
  float* out = (float*)d_out;
  const int nb = (N + 127) >> 7;

  float* ws = (float*)d_ws;
  size_t o = 0;
  float* es1   = ws + o; o += (size_t)N*4;
  float* ed1   = ws + o; o += (size_t)N*4;
  float* es2   = ws + o; o += (size_t)N;
  float* ed2   = ws + o; o += (size_t)N;
  _Float16* lxh = (_Float16*)(ws + o); o += (size_t)N*64;   // N*128 halves
  _Float16* w1t = (_Float16*)(ws + o); o += 16384;          // 32768 halves
  _Float16* w2t = (_Float16*)(ws + o); o += 8192;           // 16384 halves
  _Float16* h1h = (_Float16*)(ws + o); o += (size_t)N*128;  // N*256 halves
  _Float16* t2h = (_Float16*)(ws + o); o += (size_t)N*128;  // N*256 halves
  _Float16* h2h = (_Float16*)(ws + o); o += (size_t)N*32;   // N*64 halves
  o += (o & 1);                                             // 8B align
  half4* w0    = (half4*)(ws + o); o += (size_t)E0*2;       // E0*4 halves
  u64* temp0 = (u64*)(ws + o); o += (size_t)E0*2;
  u64* temp1 = (u64*)(ws + o); o += (size_t)E1*2;
  int* iws = (int*)(ws + o);
  size_t io = 0;
  int* rowptr0 = iws + io; io += N + 1;
  int* rowptr1 = iws + io; io += N + 1;
  int* part0   = iws + io; io += 256*NBMAX;   // partial histograms (written fully)
  int* part1   = iws + io; io += 256*NBMAX;
  int* bbase0  = iws + io; io += NBMAX + 1;
  int* bbase1  = iws + io; io += NBMAX + 1;
  int* bcur0   = iws + io; io += NBMAX;
  int* bcur1   = iws + io; io += NBMAX;
  int* csrc0   = iws + io; io += E0;
  int* csrc1   = iws + io; io += E1;

  dim3 blk(256);
  const int blocksA0 = (E0 + 4095) / 4096;
  const int blocksA1 = (E1 + 4095) / 4096;
  const int nblk1 = (N + 31) / 32;
  // merged precompute: w1t, w2t, partial dst-histograms, lx
  k_pre    <<<704 + 2048, blk, 0, stream>>>(W1, W2, x, dst0, E0, dst1, E1,
                                            w1t, w2t, part0, part1, lxh, N);
  // layer-1 GEMM on matrix cores (+ es1/ed1 epilogue) + 2 scan blocks -> bbase/bcur
  k_gemm1_mfma<<<nblk1 + 2, blk, 0, stream>>>(lxh, w1t, a_src1, a_dst1,
                                              h1h, es1, ed1,
                                              part0, part1,
                                              bbase0, bcur0, bbase1, bcur1, nb, N);
  // CSR build (+ graph-0 edge weights fused into bucketB2)
  k_bucketA<<<blocksA0 + blocksA1, blk, 0, stream>>>(
      src0, dst0, bcur0, temp0, E0, blocksA0, src1, dst1, bcur1, temp1, E1, nb);
  k_bucketB2<<<2*nb, blk, 0, stream>>>(temp0, bbase0, rowptr0, csrc0,
                                       es1, ed1, w0,
                                       temp1, bbase1, rowptr1, csrc1, N, nb);
  // layer-1 aggregation (pipelined gather, fdot2) + fused maps -> t2h
  k_agg1_csr<<<2048, blk, 0, stream>>>(rowptr0, csrc0, w0, h1h, t2h, N);
  // layer-2 GEMM on matrix cores (+ es2/ed2 epilogue)
  k_gemm2_mfma<<<(N+31)/32, blk, 0, stream>>>(t2h, w2t, a_src2, a_dst2,
                                              h2h, es2, ed2, N);
  k_agg2_csr<<<2048, blk, 0, stream>>>(rowptr1, csrc1, es2, ed2, h2h, out, N);
}